// Round 11
// baseline (778.807 us; speedup 1.0000x reference)
//
#include <hip/hip_runtime.h>

typedef unsigned short u16;
typedef __attribute__((ext_vector_type(4))) float f32x4;
typedef __attribute__((ext_vector_type(8))) short bf16x8;

#define AS1 __attribute__((address_space(1)))
#define AS3 __attribute__((address_space(3)))
#define GLL(gp, lp) __builtin_amdgcn_global_load_lds((const AS1 void*)(gp), (AS3 void*)(lp), 16, 0, 0)

__device__ __forceinline__ float b2f(u16 v) { return __uint_as_float(((unsigned)v) << 16); }
__device__ __forceinline__ u16 f2b(float f) {
  unsigned u = __float_as_uint(f);
  u += 0x7fffu + ((u >> 16) & 1u);
  return (u16)(u >> 16);
}
__device__ __forceinline__ unsigned pack2(float a, float b) {
  return (unsigned)f2b(a) | ((unsigned)f2b(b) << 16);
}
__device__ __forceinline__ float blo(unsigned u) { return __uint_as_float(u << 16); }
__device__ __forceinline__ float bhi(unsigned u) { return __uint_as_float(u & 0xffff0000u); }

// ---------------- LDS-free GEMM for big clean shapes (QKV, O-proj) ----------------
// C[M,N] = A[M,K]*Bt[N,K]^T + bias. 4 waves 2x2, wave tile 64x64, acc[4][4].
// MFMA fragments load DIRECT from global (the win_attn Q/K pattern, verified R3+):
// lane lm reads row mi*16+lm, k-chunk lg*8 -> one 16B load per fragment.
// No LDS, no barriers, no swizzle: R9's accounting showed ~75% of the GEMM window
// was LDS pipe + 2 barriers/K-step; here the compiler pipelines loads freely.
// B (weights) is L2-resident; XCD remap makes A strips L2-local; block-internal
// 2x duplication is L1-absorbed.
__global__ __launch_bounds__(256) void gemm_direct(
    const u16* __restrict__ A, int lda,
    const u16* __restrict__ Bt, int ldb,
    const float* __restrict__ bias, void* __restrict__ Cv, int ldc,
    int M, int N, int K, int c_bf16)
{
  int tid = threadIdx.x;
  int wid = tid >> 6, lane = tid & 63;
  int lm = lane & 15, lg = lane >> 4;

  // XCD-aware bijective remap
  int nbx = gridDim.x;
  int lin = blockIdx.y * nbx + blockIdx.x;
  int nwg = nbx * gridDim.y;
  int qc = nwg >> 3, rc = nwg & 7;
  int xcd = lin & 7, pos = lin >> 3;
  int nlin = (xcd < rc ? xcd * (qc + 1) : rc * (qc + 1) + (xcd - rc) * qc) + pos;
  int bx = nlin % nbx, by = nlin / nbx;

  int row0 = (by << 7) + ((wid >> 1) << 6);
  int col0 = (bx << 7) + ((wid & 1) << 6);

  const u16* pa[4];
  const u16* pb[4];
#pragma unroll
  for (int mi = 0; mi < 4; ++mi) {
    int r = row0 + mi * 16 + lm; r = r < M ? r : M - 1;
    pa[mi] = A + (size_t)r * lda + lg * 8;
  }
#pragma unroll
  for (int ni = 0; ni < 4; ++ni) {
    int c = col0 + ni * 16 + lm; c = c < N ? c : N - 1;
    pb[ni] = Bt + (size_t)c * ldb + lg * 8;
  }

  f32x4 acc[4][4];
#pragma unroll
  for (int i = 0; i < 4; ++i)
#pragma unroll
    for (int j = 0; j < 4; ++j) { f32x4 z = {0.f, 0.f, 0.f, 0.f}; acc[i][j] = z; }

  for (int kt = 0; kt < K; kt += 32) {
    bf16x8 af[4], bg[4];
#pragma unroll
    for (int mi = 0; mi < 4; ++mi) { af[mi] = *(const bf16x8*)(pa[mi]); pa[mi] += 32; }
#pragma unroll
    for (int ni = 0; ni < 4; ++ni) { bg[ni] = *(const bf16x8*)(pb[ni]); pb[ni] += 32; }
#pragma unroll
    for (int mi = 0; mi < 4; ++mi)
#pragma unroll
      for (int ni = 0; ni < 4; ++ni)
        acc[mi][ni] = __builtin_amdgcn_mfma_f32_16x16x32_bf16(af[mi], bg[ni], acc[mi][ni], 0, 0, 0);
  }

#pragma unroll
  for (int mi = 0; mi < 4; ++mi) {
    int rb = row0 + (mi << 4) + (lg << 2);
#pragma unroll
    for (int ni = 0; ni < 4; ++ni) {
      int c = col0 + (ni << 4) + lm;
      float bv = (bias && c < N) ? bias[c] : 0.f;
#pragma unroll
      for (int j = 0; j < 4; ++j) {
        int r = rb + j;
        if (r < M && c < N) {
          float v = acc[mi][ni][j] + bv;
          if (c_bf16) ((u16*)Cv)[(size_t)r * ldc + c] = f2b(v);
          else ((float*)Cv)[(size_t)r * ldc + c] = v;
        }
      }
    }
  }
}

// ---------------- 128x64-tile GEMM (R9, proven): batched / odd shapes ----------------
__global__ __launch_bounds__(256, 6) void gemm_bt(
    const u16* __restrict__ A, int lda, long sAb,
    const u16* __restrict__ Bt, int ldb, long sBb,
    const float* __restrict__ bias, void* __restrict__ Cv, int ldc, long sCb,
    int M, int N, int K, int c_bf16)
{
  __shared__ __align__(16) u16 ldsA[128 * 64];
  __shared__ __align__(16) u16 ldsB[64 * 64];
  int tid = threadIdx.x;
  int wid = tid >> 6, lane = tid & 63;

  int nbx = gridDim.x;
  int lin = blockIdx.y * nbx + blockIdx.x;
  int nwg = nbx * gridDim.y;
  int qc = nwg >> 3, rc = nwg & 7;
  int xcd = lin & 7, pos = lin >> 3;
  int nlin = (xcd < rc ? xcd * (qc + 1) : rc * (qc + 1) + (xcd - rc) * qc) + pos;
  int bx = nlin % nbx, by = nlin / nbx;

  int row0 = by << 7;
  int col0 = bx << 6;
  int bz = blockIdx.z;
  A += (size_t)bz * sAb;
  Bt += (size_t)bz * sBb;
  int wr = (wid >> 1) << 6, wc = (wid & 1) << 5;

  const u16* pA[4];
  const u16* pB[2];
  int ldsoA[4], ldsoB[2];
#pragma unroll
  for (int q = 0; q < 4; ++q) {
    int inst = (wid << 2) + q;
    int o = (inst << 10) + (lane << 4);
    int r = o >> 7;
    int cs = (o >> 4) & 7;
    int cl = cs ^ (r & 7);
    int ar = row0 + r; ar = ar < M ? ar : M - 1;
    pA[q] = A + (size_t)ar * lda + (cl << 3);
    ldsoA[q] = inst << 9;
  }
#pragma unroll
  for (int q = 0; q < 2; ++q) {
    int inst = (wid << 1) + q;
    int o = (inst << 10) + (lane << 4);
    int r = o >> 7;
    int cs = (o >> 4) & 7;
    int cl = cs ^ (r & 7);
    int br = col0 + r; br = br < N ? br : N - 1;
    pB[q] = Bt + (size_t)br * ldb + (cl << 3);
    ldsoB[q] = inst << 9;
  }

  f32x4 acc[4][2];
#pragma unroll
  for (int i = 0; i < 4; ++i)
#pragma unroll
    for (int j = 0; j < 2; ++j) { f32x4 z = {0.f, 0.f, 0.f, 0.f}; acc[i][j] = z; }

  int nt = K >> 6;
  for (int t = 0; t < nt; ++t) {
#pragma unroll
    for (int q = 0; q < 4; ++q) { GLL(pA[q], ldsA + ldsoA[q]); pA[q] += 64; }
#pragma unroll
    for (int q = 0; q < 2; ++q) { GLL(pB[q], ldsB + ldsoB[q]); pB[q] += 64; }
    __syncthreads();
#pragma unroll
    for (int kk = 0; kk < 2; ++kk) {
      bf16x8 af[4], bg[2];
#pragma unroll
      for (int mi = 0; mi < 4; ++mi) {
        int r = wr + (mi << 4) + (lane & 15);
        int cs = ((kk << 2) + (lane >> 4)) ^ (r & 7);
        af[mi] = *(const bf16x8*)(ldsA + (r << 6) + (cs << 3));
      }
#pragma unroll
      for (int ni = 0; ni < 2; ++ni) {
        int r = wc + (ni << 4) + (lane & 15);
        int cs = ((kk << 2) + (lane >> 4)) ^ (r & 7);
        bg[ni] = *(const bf16x8*)(ldsB + (r << 6) + (cs << 3));
      }
#pragma unroll
      for (int mi = 0; mi < 4; ++mi)
#pragma unroll
        for (int ni = 0; ni < 2; ++ni)
          acc[mi][ni] = __builtin_amdgcn_mfma_f32_16x16x32_bf16(af[mi], bg[ni], acc[mi][ni], 0, 0, 0);
    }
    __syncthreads();
  }

#pragma unroll
  for (int mi = 0; mi < 4; ++mi) {
    int rb = row0 + wr + (mi << 4) + ((lane >> 4) << 2);
#pragma unroll
    for (int ni = 0; ni < 2; ++ni) {
      int c = col0 + wc + (ni << 4) + (lane & 15);
      float bv = (bias && c < N) ? bias[c] : 0.f;
#pragma unroll
      for (int j = 0; j < 4; ++j) {
        int r = rb + j;
        if (r < M && c < N) {
          float v = acc[mi][ni][j] + bv;
          if (c_bf16) ((u16*)Cv)[(size_t)bz * sCb + (size_t)r * ldc + c] = f2b(v);
          else ((float*)Cv)[(size_t)bz * sCb + (size_t)r * ldc + c] = v;
        }
      }
    }
  }
}

// ---------------- window attention via MFMA: 1 block per window, wave = head group ----------------
__global__ __launch_bounds__(256, 2) void win_attn_mfma(const u16* __restrict__ qkv, u16* __restrict__ oat)
{
  __shared__ __align__(16) u16 Pl[4][64 * 72];
  __shared__ __align__(16) u16 Vtl[4][32 * 72];
  int tid = threadIdx.x;
  int wid = tid >> 6, lane = tid & 63;
  int lm = lane & 15, lg = lane >> 4;
  int w = blockIdx.x;
  int b = w >> 8, wh = (w >> 4) & 15, ww = w & 15;
  int rowbase = (wh * 7) * 112 + ww * 7;
  u16* P = Pl[wid];
  u16* Vt = Vtl[wid];
  const u16* base = qkv + (size_t)b * 12544 * 1536;
  u16* ob = oat + (size_t)b * 12544 * 512;
  const float scale = 0.17677669529663687f;

  for (int hh = 0; hh < 4; ++hh) {
    int h = wid * 4 + hh;
    bf16x8 Qf[4], Kf[4];
#pragma unroll
    for (int mi = 0; mi < 4; ++mi) {
      int i = mi * 16 + lm; i = i < 49 ? i : 48;
      int q7 = (i * 147) >> 10;
      int n = rowbase + q7 * 112 + (i - q7 * 7);
      const u16* rp = base + (size_t)n * 1536 + h * 32 + lg * 8;
      Qf[mi] = *(const bf16x8*)(rp);
      Kf[mi] = *(const bf16x8*)(rp + 512);
    }
    {
      int j = lane;
      if (j < 49) {
        int q7 = (j * 147) >> 10;
        int n = rowbase + q7 * 112 + (j - q7 * 7);
        const uint4* vp = (const uint4*)(base + (size_t)n * 1536 + 1024 + h * 32);
#pragma unroll
        for (int t = 0; t < 4; ++t) {
          uint4 u = vp[t];
          Vt[(t * 8 + 0) * 72 + j] = (u16)(u.x & 0xffff); Vt[(t * 8 + 1) * 72 + j] = (u16)(u.x >> 16);
          Vt[(t * 8 + 2) * 72 + j] = (u16)(u.y & 0xffff); Vt[(t * 8 + 3) * 72 + j] = (u16)(u.y >> 16);
          Vt[(t * 8 + 4) * 72 + j] = (u16)(u.z & 0xffff); Vt[(t * 8 + 5) * 72 + j] = (u16)(u.z >> 16);
          Vt[(t * 8 + 6) * 72 + j] = (u16)(u.w & 0xffff); Vt[(t * 8 + 7) * 72 + j] = (u16)(u.w >> 16);
        }
      } else {
#pragma unroll
        for (int d = 0; d < 32; ++d) Vt[d * 72 + j] = 0;
      }
    }
    f32x4 S[4][4];
#pragma unroll
    for (int mi = 0; mi < 4; ++mi)
#pragma unroll
      for (int nj = 0; nj < 4; ++nj) { f32x4 z = {0.f, 0.f, 0.f, 0.f}; S[mi][nj] = z; }
#pragma unroll
    for (int mi = 0; mi < 4; ++mi)
#pragma unroll
      for (int nj = 0; nj < 4; ++nj)
        S[mi][nj] = __builtin_amdgcn_mfma_f32_16x16x32_bf16(Qf[mi], Kf[nj], S[mi][nj], 0, 0, 0);
    float invv[4][4];
#pragma unroll
    for (int mi = 0; mi < 4; ++mi) {
#pragma unroll
      for (int reg = 0; reg < 4; ++reg) {
        float v0 = S[mi][0][reg], v1 = S[mi][1][reg], v2 = S[mi][2][reg], v3 = S[mi][3][reg];
        if (lm) v3 = -1e30f;
        float m = fmaxf(fmaxf(v0, v1), fmaxf(v2, v3));
#pragma unroll
        for (int o = 1; o < 16; o <<= 1) m = fmaxf(m, __shfl_xor(m, o));
        float e0 = __expf((v0 - m) * scale);
        float e1 = __expf((v1 - m) * scale);
        float e2 = __expf((v2 - m) * scale);
        float e3 = lm ? 0.f : __expf((v3 - m) * scale);
        float s = e0 + e1 + e2 + e3;
#pragma unroll
        for (int o = 1; o < 16; o <<= 1) s += __shfl_xor(s, o);
        invv[mi][reg] = 1.f / s;
        int r = mi * 16 + lg * 4 + reg;
        P[r * 72 + lm] = f2b(e0);
        P[r * 72 + 16 + lm] = f2b(e1);
        P[r * 72 + 32 + lm] = f2b(e2);
        P[r * 72 + 48 + lm] = f2b(e3);
      }
    }
    bf16x8 Vf[2][2];
#pragma unroll
    for (int dt = 0; dt < 2; ++dt) {
      Vf[dt][0] = *(const bf16x8*)(Vt + (dt * 16 + lm) * 72 + lg * 8);
      Vf[dt][1] = *(const bf16x8*)(Vt + (dt * 16 + lm) * 72 + 32 + lg * 8);
    }
    f32x4 O[4][2];
#pragma unroll
    for (int mi = 0; mi < 4; ++mi)
#pragma unroll
      for (int dt = 0; dt < 2; ++dt) { f32x4 z = {0.f, 0.f, 0.f, 0.f}; O[mi][dt] = z; }
#pragma unroll
    for (int mi = 0; mi < 4; ++mi) {
      bf16x8 Pf0 = *(const bf16x8*)(P + (mi * 16 + lm) * 72 + lg * 8);
      bf16x8 Pf1 = *(const bf16x8*)(P + (mi * 16 + lm) * 72 + 32 + lg * 8);
#pragma unroll
      for (int dt = 0; dt < 2; ++dt) {
        O[mi][dt] = __builtin_amdgcn_mfma_f32_16x16x32_bf16(Pf0, Vf[dt][0], O[mi][dt], 0, 0, 0);
        O[mi][dt] = __builtin_amdgcn_mfma_f32_16x16x32_bf16(Pf1, Vf[dt][1], O[mi][dt], 0, 0, 0);
      }
    }
#pragma unroll
    for (int mi = 0; mi < 4; ++mi)
#pragma unroll
      for (int reg = 0; reg < 4; ++reg) {
        int i = mi * 16 + lg * 4 + reg;
        if (i < 49) {
          int q7 = (i * 147) >> 10;
          int n = rowbase + q7 * 112 + (i - q7 * 7);
          float iv = invv[mi][reg];
          u16* op = ob + (size_t)n * 512 + h * 32 + lm;
          op[0] = f2b(O[mi][0][reg] * iv);
          op[16] = f2b(O[mi][1][reg] * iv);
        }
      }
  }
}

// ---------------- DCT of 8x8 patches at subsampled positions -> F2 (3136 x 192) bf16 ----------------
__global__ __launch_bounds__(192) void dct_f2(const float* __restrict__ patches, u16* __restrict__ F2)
{
  __shared__ float pv[192];
  __shared__ float Bm[64];
  int blk = blockIdx.x;
  int b = blk / 784, rem = blk % 784;
  int n = ((rem / 28) * 4) * 112 + (rem % 28) * 4;
  int t = threadIdx.x;
  if (t < 64) {
    int k = t >> 3, ii = t & 7;
    float v = cosf(3.14159265358979323846f * (ii + 0.5f) * (float)k * 0.125f) * 0.5f;
    if (k == 0) v *= 0.70710678118654752f;
    Bm[t] = v;
  }
  pv[t] = patches[((size_t)b * 192 + t) * 12544 + n];
  __syncthreads();
  int c = t >> 6, fi = (t >> 3) & 7, fk = t & 7;
  float acc = 0.f;
#pragma unroll
  for (int mm = 0; mm < 8; ++mm) {
    float g = 0.f;
#pragma unroll
    for (int jj = 0; jj < 8; ++jj) g += pv[c * 64 + mm * 8 + jj] * Bm[jj * 8 + fk];
    acc += Bm[fi * 8 + mm] * g;
  }
  F2[(size_t)blk * 192 + t] = f2b(acc);
}

// ---------------- spectral softmax: 1 block per row, 784 cols -> bf16 P (padded to 832) ----------------
__global__ __launch_bounds__(256) void spec_softmax(const float* __restrict__ S, u16* __restrict__ P)
{
  __shared__ float red[4];
  int row = blockIdx.x;
  const float* sr = S + (size_t)row * 784;
  u16* pr = P + (size_t)row * 832;
  int t = threadIdx.x;
  int lane = t & 63, wid = t >> 6;
  float v0 = sr[t];
  float v1 = sr[t + 256];
  float v2 = (t < 272) ? sr[t + 512] : -1e30f;
  float m = fmaxf(fmaxf(v0, v1), v2);
#pragma unroll
  for (int ofs = 32; ofs > 0; ofs >>= 1) m = fmaxf(m, __shfl_xor(m, ofs));
  if (lane == 0) red[wid] = m;
  __syncthreads();
  m = fmaxf(fmaxf(red[0], red[1]), fmaxf(red[2], red[3]));
  __syncthreads();
  const float scale = 0.044194173824159216f;
  float e0 = __expf((v0 - m) * scale);
  float e1 = __expf((v1 - m) * scale);
  float e2 = (t < 272) ? __expf((v2 - m) * scale) : 0.f;
  float sum = e0 + e1 + e2;
#pragma unroll
  for (int ofs = 32; ofs > 0; ofs >>= 1) sum += __shfl_xor(sum, ofs);
  if (lane == 0) red[wid] = sum;
  __syncthreads();
  sum = red[0] + red[1] + red[2] + red[3];
  float inv = 1.f / sum;
  pr[t] = f2b(e0 * inv);
  pr[t + 256] = f2b(e1 * inv);
  if (t < 272) pr[t + 512] = f2b(e2 * inv);
  else if (t < 320) pr[t + 512] = 0;
}

// ---------------- V transpose for PV gemm: Vt[b][n][k] = V[b][k][n], k padded to 832 ----------------
__global__ __launch_bounds__(256) void transV(const u16* __restrict__ qkvs, u16* __restrict__ Vt)
{
  int idx = blockIdx.x * 256 + threadIdx.x;
  int k = idx % 832;
  int rest = idx / 832;
  int n = rest % 512, b = rest / 512;
  u16 v = 0;
  if (k < 784) v = qkvs[((size_t)(b * 784 + k)) * 1536 + 1024 + n];
  Vt[idx] = v;
}

// ---------------- combine + nearest-upsample gather + LayerNorm ----------------
__global__ __launch_bounds__(256) void combine_ln(
    const float* __restrict__ tokens, const u16* __restrict__ sp,
    const float* __restrict__ so, const float* __restrict__ alpha,
    float* __restrict__ out)
{
  int nidx = blockIdx.x;
  int b = nidx / 12544, pos = nidx % 12544;
  int i = pos / 112, j = pos % 112;
  const float* tr = tokens + (size_t)nidx * 512;
  const u16* sr = sp + (size_t)nidx * 512;
  const float* qr = so + (size_t)(b * 784 + (i >> 2) * 28 + (j >> 2)) * 512;
  float al = 1.f / (1.f + __expf(-alpha[0]));
  float be = 1.f - al;
  int t = threadIdx.x;
  float x0 = tr[t] + al * b2f(sr[t]) + be * qr[t];
  float x1 = tr[t + 256] + al * b2f(sr[t + 256]) + be * qr[t + 256];
  float s = x0 + x1, ss = x0 * x0 + x1 * x1;
#pragma unroll
  for (int ofs = 32; ofs > 0; ofs >>= 1) { s += __shfl_xor(s, ofs); ss += __shfl_xor(ss, ofs); }
  __shared__ float rs[4], rq[4];
  int lane = t & 63, wid = t >> 6;
  if (lane == 0) { rs[wid] = s; rq[wid] = ss; }
  __syncthreads();
  s = rs[0] + rs[1] + rs[2] + rs[3];
  ss = rq[0] + rq[1] + rq[2] + rq[3];
  float mu = s * 0.001953125f;
  float var = ss * 0.001953125f - mu * mu;
  float rstd = rsqrtf(var + 1e-5f);
  float* orow = out + (size_t)nidx * 512;
  orow[t] = (x0 - mu) * rstd;
  orow[t + 256] = (x1 - mu) * rstd;
}

// ---------------- coalesced tiled transpose: dst[n*K+k] = f2b(src[k*Nc+n]) ----------------
__global__ __launch_bounds__(256) void transT(const float* __restrict__ src, u16* __restrict__ dst, int K, int Nc)
{
  __shared__ float tile[64][65];
  int tk0 = blockIdx.y << 6, tn0 = blockIdx.x << 6;
  int j = threadIdx.x & 63, i4 = threadIdx.x >> 6;
#pragma unroll
  for (int i = i4; i < 64; i += 4) {
    int k = tk0 + i, n = tn0 + j;
    tile[i][j] = (k < K && n < Nc) ? src[(size_t)k * Nc + n] : 0.f;
  }
  __syncthreads();
#pragma unroll
  for (int i = i4; i < 64; i += 4) {
    int n = tn0 + i, k = tk0 + j;
    if (n < Nc && k < K) dst[(size_t)n * K + k] = f2b(tile[j][i]);
  }
}

__global__ __launch_bounds__(256) void cvtbf(const float* __restrict__ src, u16* __restrict__ dst)
{
  size_t i = ((size_t)blockIdx.x * 256 + threadIdx.x) * 4;
  float4 v = *(const float4*)(src + i);
  uint2 u;
  u.x = pack2(v.x, v.y);
  u.y = pack2(v.z, v.w);
  *(uint2*)(dst + i) = u;
}

__global__ __launch_bounds__(256) void stack_bias(
    const float* bq_, const float* bk_, const float* bv_,
    const float* bsq_, const float* bsk_, const float* bsv_,
    float* bqkv, float* bsqkv)
{
  int i = blockIdx.x * 256 + threadIdx.x;
  if (i >= 1536) return;
  int r = i & 511;
  bqkv[i]  = (i < 512) ? bq_[r]  : (i < 1024) ? bk_[r]  : bv_[r];
  bsqkv[i] = (i < 512) ? bsq_[r] : (i < 1024) ? bsk_[r] : bsv_[r];
}

// ---------------- launch ----------------
extern "C" void kernel_launch(void* const* d_in, const int* in_sizes, int n_in,
                              void* d_out, int out_size, void* d_ws, size_t ws_size,
                              hipStream_t stream) {
  (void)in_sizes; (void)n_in; (void)out_size; (void)ws_size;
  const float* tokens = (const float*)d_in[0];
  const float* patches = (const float*)d_in[1];
  const float* Wq  = (const float*)d_in[2];
  const float* bq  = (const float*)d_in[3];
  const float* Wk  = (const float*)d_in[4];
  const float* bk  = (const float*)d_in[5];
  const float* Wv  = (const float*)d_in[6];
  const float* bv  = (const float*)d_in[7];
  const float* Wo  = (const float*)d_in[8];
  const float* bo  = (const float*)d_in[9];
  const float* Wsp = (const float*)d_in[10];
  const float* bsp = (const float*)d_in[11];
  const float* Wsq = (const float*)d_in[12];
  const float* bsq = (const float*)d_in[13];
  const float* Wsk = (const float*)d_in[14];
  const float* bsk = (const float*)d_in[15];
  const float* Wsv = (const float*)d_in[16];
  const float* bsv = (const float*)d_in[17];
  const float* Wso = (const float*)d_in[18];
  const float* bso = (const float*)d_in[19];
  const float* alpha = (const float*)d_in[20];
  float* out = (float*)d_out;

  char* ws = (char*)d_ws;
  u16* tokbf  = (u16*)ws;
  u16* qkv    = (u16*)(ws + 51380224);
  char* pp    = ws + 51380224 + 154140672;
  u16* WqkvT  = (u16*)pp; pp += 1572864;
  u16* WoT    = (u16*)pp; pp += 524288;
  u16* WsqkvT = (u16*)pp; pp += 1572864;
  u16* WsoT   = (u16*)pp; pp += 524288;
  u16* WspT   = (u16*)pp; pp += 196608;
  float* bqkv = (float*)pp; pp += 6144;
  float* bsqkv= (float*)pp; pp += 6144;
  u16* F2b    = (u16*)pp; pp += 1204224;
  u16* sd     = (u16*)pp; pp += 3211264;
  u16* qkvs   = (u16*)pp; pp += 9633792;
  u16* sopre  = (u16*)pp; pp += 3211264;
  float* sofin= (float*)pp; pp += 6422528;

  float* Sbuf = (float*)tokbf;
  u16* Pbuf   = (u16*)(ws + 9834496);
  u16* Vt     = (u16*)(ws + 9834496 + 5218304);

  // prep (coalesced tiled transposes)
  cvtbf<<<25088, 256, 0, stream>>>(tokens, tokbf);
  transT<<<dim3(8, 8), 256, 0, stream>>>(Wq, WqkvT, 512, 512);
  transT<<<dim3(8, 8), 256, 0, stream>>>(Wk, WqkvT + 262144, 512, 512);
  transT<<<dim3(8, 8), 256, 0, stream>>>(Wv, WqkvT + 524288, 512, 512);
  transT<<<dim3(8, 8), 256, 0, stream>>>(Wo, WoT, 512, 512);
  transT<<<dim3(8, 8), 256, 0, stream>>>(Wsq, WsqkvT, 512, 512);
  transT<<<dim3(8, 8), 256, 0, stream>>>(Wsk, WsqkvT + 262144, 512, 512);
  transT<<<dim3(8, 8), 256, 0, stream>>>(Wsv, WsqkvT + 524288, 512, 512);
  transT<<<dim3(8, 8), 256, 0, stream>>>(Wso, WsoT, 512, 512);
  transT<<<dim3(8, 3), 256, 0, stream>>>(Wsp, WspT, 192, 512);
  stack_bias<<<6, 256, 0, stream>>>(bq, bk, bv, bsq, bsk, bsv, bqkv, bsqkv);

  // spatial path: LDS-free direct-fragment GEMMs
  gemm_direct<<<dim3(12, 392), 256, 0, stream>>>(tokbf, 512, WqkvT, 512, bqkv, qkv, 1536, 50176, 1536, 512, 1);
  win_attn_mfma<<<1024, 256, 0, stream>>>(qkv, tokbf);
  gemm_direct<<<dim3(4, 392), 256, 0, stream>>>(tokbf, 512, WoT, 512, bo, qkv, 512, 50176, 512, 512, 1);

  // spectral path (proven R9 gemm_bt)
  dct_f2<<<3136, 192, 0, stream>>>(patches, F2b);
  gemm_bt<<<dim3(8, 25), 256, 0, stream>>>(F2b, 192, 0, WspT, 192, 0, bsp, sd, 512, 0, 3136, 512, 192, 1);
  gemm_bt<<<dim3(24, 25), 256, 0, stream>>>(sd, 512, 0, WsqkvT, 512, 0, bsqkv, qkvs, 1536, 0, 3136, 1536, 512, 1);
  gemm_bt<<<dim3(13, 7, 4), 256, 0, stream>>>(qkvs, 1536, (long)784 * 1536, qkvs + 512, 1536, (long)784 * 1536,
                                              nullptr, Sbuf, 784, (long)784 * 784, 784, 784, 512, 0);
  spec_softmax<<<3136, 256, 0, stream>>>(Sbuf, Pbuf);
  transV<<<6656, 256, 0, stream>>>(qkvs, Vt);
  gemm_bt<<<dim3(8, 7, 4), 256, 0, stream>>>(Pbuf, 832, (long)784 * 832, Vt, 832, (long)512 * 832,
                                             nullptr, sopre, 512, (long)784 * 512, 784, 512, 832, 1);
  gemm_bt<<<dim3(8, 25), 256, 0, stream>>>(sopre, 512, 0, WsoT, 512, 0, bso, sofin, 512, 0, 3136, 512, 512, 0);

  // combine + LN
  combine_ln<<<50176, 256, 0, stream>>>(tokens, qkv, sofin, alpha, out);
}

// Round 12
// 522.880 us; speedup vs baseline: 1.4895x; 1.4895x over previous
//
#include <hip/hip_runtime.h>

typedef unsigned short u16;
typedef __attribute__((ext_vector_type(4))) float f32x4;
typedef __attribute__((ext_vector_type(8))) short bf16x8;

#define AS1 __attribute__((address_space(1)))
#define AS3 __attribute__((address_space(3)))
#define GLL(gp, lp) __builtin_amdgcn_global_load_lds((const AS1 void*)(gp), (AS3 void*)(lp), 16, 0, 0)

__device__ __forceinline__ float b2f(u16 v) { return __uint_as_float(((unsigned)v) << 16); }
__device__ __forceinline__ u16 f2b(float f) {
  unsigned u = __float_as_uint(f);
  u += 0x7fffu + ((u >> 16) & 1u);
  return (u16)(u >> 16);
}
__device__ __forceinline__ unsigned pack2(float a, float b) {
  return (unsigned)f2b(a) | ((unsigned)f2b(b) << 16);
}
__device__ __forceinline__ float blo(unsigned u) { return __uint_as_float(u << 16); }
__device__ __forceinline__ float bhi(unsigned u) { return __uint_as_float(u & 0xffff0000u); }

// ---------------- 512-thread 128x128-tile GEMM (QKV / O-proj experiment) ----------------
// Same proven single-buffer 2-barrier loop as R9, but 8 waves (2x4) share one 128x128
// tile: per-wave 64x32 output, acc[4][2]=32 AGPR. Register audit: ~40 VGPR + 32 AGPR
// = 72 <= 512/6 = 85 at launch_bounds(512,6) -> 3 blocks/CU (24 waves, same occ as R9)
// with +18% LDS arithmetic intensity and -36% staged bytes/FLOP (tile shared 8-way).
__global__ __launch_bounds__(512, 6) void gemm_bt512(
    const u16* __restrict__ A, int lda,
    const u16* __restrict__ Bt, int ldb,
    const float* __restrict__ bias, void* __restrict__ Cv, int ldc,
    int M, int N, int K, int c_bf16)
{
  __shared__ __align__(16) u16 ldsA[128 * 64];
  __shared__ __align__(16) u16 ldsB[128 * 64];
  int tid = threadIdx.x;
  int wid = tid >> 6, lane = tid & 63;
  int lm = lane & 15, lg = lane >> 4;
  int wm = wid >> 2, wn = wid & 3;

  // XCD-aware bijective remap
  int nbx = gridDim.x;
  int lin = blockIdx.y * nbx + blockIdx.x;
  int nwg = nbx * gridDim.y;
  int qc = nwg >> 3, rc = nwg & 7;
  int xcd = lin & 7, pos = lin >> 3;
  int nlin = (xcd < rc ? xcd * (qc + 1) : rc * (qc + 1) + (xcd - rc) * qc) + pos;
  int bx = nlin % nbx, by = nlin / nbx;

  int row0 = by << 7;
  int col0 = bx << 7;
  int wr = wm << 6, wc = wn << 5;

  // staging: A/B tiles are each 16KB = 2 rounds x 512 threads x 16B (wave-contiguous 1KB)
  const u16* pA[2];
  const u16* pB[2];
  int ldso[2];
#pragma unroll
  for (int q = 0; q < 2; ++q) {
    int o = (q << 13) + (tid << 4);       // byte offset in tile
    int r = o >> 7;                       // row (128B per row)
    int cs = (o >> 4) & 7;                // stored 16B chunk
    int cl = cs ^ (r & 7);                // pre-swizzled source chunk
    int ar = row0 + r; ar = ar < M ? ar : M - 1;
    int br = col0 + r; br = br < N ? br : N - 1;
    pA[q] = A + (size_t)ar * lda + (cl << 3);
    pB[q] = Bt + (size_t)br * ldb + (cl << 3);
    ldso[q] = o >> 1;                     // elem offset
  }

  f32x4 acc[4][2];
#pragma unroll
  for (int i = 0; i < 4; ++i)
#pragma unroll
    for (int j = 0; j < 2; ++j) { f32x4 z = {0.f, 0.f, 0.f, 0.f}; acc[i][j] = z; }

  int nt = K >> 6;
  for (int t = 0; t < nt; ++t) {
#pragma unroll
    for (int q = 0; q < 2; ++q) {
      GLL(pA[q], ldsA + ldso[q]);
      GLL(pB[q], ldsB + ldso[q]);
      pA[q] += 64; pB[q] += 64;
    }
    __syncthreads();
#pragma unroll
    for (int kk = 0; kk < 2; ++kk) {
      bf16x8 af[4], bg[2];
#pragma unroll
      for (int mi = 0; mi < 4; ++mi) {
        int r = wr + (mi << 4) + lm;
        int cs = ((kk << 2) + lg) ^ (r & 7);
        af[mi] = *(const bf16x8*)(ldsA + (r << 6) + (cs << 3));
      }
#pragma unroll
      for (int ni = 0; ni < 2; ++ni) {
        int r = wc + (ni << 4) + lm;
        int cs = ((kk << 2) + lg) ^ (r & 7);
        bg[ni] = *(const bf16x8*)(ldsB + (r << 6) + (cs << 3));
      }
#pragma unroll
      for (int mi = 0; mi < 4; ++mi)
#pragma unroll
        for (int ni = 0; ni < 2; ++ni)
          acc[mi][ni] = __builtin_amdgcn_mfma_f32_16x16x32_bf16(af[mi], bg[ni], acc[mi][ni], 0, 0, 0);
    }
    __syncthreads();
  }

#pragma unroll
  for (int mi = 0; mi < 4; ++mi) {
    int rb = row0 + wr + (mi << 4) + (lg << 2);
#pragma unroll
    for (int ni = 0; ni < 2; ++ni) {
      int c = col0 + wc + (ni << 4) + lm;
      float bv = (bias && c < N) ? bias[c] : 0.f;
#pragma unroll
      for (int j = 0; j < 4; ++j) {
        int r = rb + j;
        if (r < M && c < N) {
          float v = acc[mi][ni][j] + bv;
          if (c_bf16) ((u16*)Cv)[(size_t)r * ldc + c] = f2b(v);
          else ((float*)Cv)[(size_t)r * ldc + c] = v;
        }
      }
    }
  }
}

// ---------------- 128x64-tile GEMM (R9, proven): batched / odd shapes ----------------
__global__ __launch_bounds__(256, 6) void gemm_bt(
    const u16* __restrict__ A, int lda, long sAb,
    const u16* __restrict__ Bt, int ldb, long sBb,
    const float* __restrict__ bias, void* __restrict__ Cv, int ldc, long sCb,
    int M, int N, int K, int c_bf16)
{
  __shared__ __align__(16) u16 ldsA[128 * 64];
  __shared__ __align__(16) u16 ldsB[64 * 64];
  int tid = threadIdx.x;
  int wid = tid >> 6, lane = tid & 63;

  int nbx = gridDim.x;
  int lin = blockIdx.y * nbx + blockIdx.x;
  int nwg = nbx * gridDim.y;
  int qc = nwg >> 3, rc = nwg & 7;
  int xcd = lin & 7, pos = lin >> 3;
  int nlin = (xcd < rc ? xcd * (qc + 1) : rc * (qc + 1) + (xcd - rc) * qc) + pos;
  int bx = nlin % nbx, by = nlin / nbx;

  int row0 = by << 7;
  int col0 = bx << 6;
  int bz = blockIdx.z;
  A += (size_t)bz * sAb;
  Bt += (size_t)bz * sBb;
  int wr = (wid >> 1) << 6, wc = (wid & 1) << 5;

  const u16* pA[4];
  const u16* pB[2];
  int ldsoA[4], ldsoB[2];
#pragma unroll
  for (int q = 0; q < 4; ++q) {
    int inst = (wid << 2) + q;
    int o = (inst << 10) + (lane << 4);
    int r = o >> 7;
    int cs = (o >> 4) & 7;
    int cl = cs ^ (r & 7);
    int ar = row0 + r; ar = ar < M ? ar : M - 1;
    pA[q] = A + (size_t)ar * lda + (cl << 3);
    ldsoA[q] = inst << 9;
  }
#pragma unroll
  for (int q = 0; q < 2; ++q) {
    int inst = (wid << 1) + q;
    int o = (inst << 10) + (lane << 4);
    int r = o >> 7;
    int cs = (o >> 4) & 7;
    int cl = cs ^ (r & 7);
    int br = col0 + r; br = br < N ? br : N - 1;
    pB[q] = Bt + (size_t)br * ldb + (cl << 3);
    ldsoB[q] = inst << 9;
  }

  f32x4 acc[4][2];
#pragma unroll
  for (int i = 0; i < 4; ++i)
#pragma unroll
    for (int j = 0; j < 2; ++j) { f32x4 z = {0.f, 0.f, 0.f, 0.f}; acc[i][j] = z; }

  int nt = K >> 6;
  for (int t = 0; t < nt; ++t) {
#pragma unroll
    for (int q = 0; q < 4; ++q) { GLL(pA[q], ldsA + ldsoA[q]); pA[q] += 64; }
#pragma unroll
    for (int q = 0; q < 2; ++q) { GLL(pB[q], ldsB + ldsoB[q]); pB[q] += 64; }
    __syncthreads();
#pragma unroll
    for (int kk = 0; kk < 2; ++kk) {
      bf16x8 af[4], bg[2];
#pragma unroll
      for (int mi = 0; mi < 4; ++mi) {
        int r = wr + (mi << 4) + (lane & 15);
        int cs = ((kk << 2) + (lane >> 4)) ^ (r & 7);
        af[mi] = *(const bf16x8*)(ldsA + (r << 6) + (cs << 3));
      }
#pragma unroll
      for (int ni = 0; ni < 2; ++ni) {
        int r = wc + (ni << 4) + (lane & 15);
        int cs = ((kk << 2) + (lane >> 4)) ^ (r & 7);
        bg[ni] = *(const bf16x8*)(ldsB + (r << 6) + (cs << 3));
      }
#pragma unroll
      for (int mi = 0; mi < 4; ++mi)
#pragma unroll
        for (int ni = 0; ni < 2; ++ni)
          acc[mi][ni] = __builtin_amdgcn_mfma_f32_16x16x32_bf16(af[mi], bg[ni], acc[mi][ni], 0, 0, 0);
    }
    __syncthreads();
  }

#pragma unroll
  for (int mi = 0; mi < 4; ++mi) {
    int rb = row0 + wr + (mi << 4) + ((lane >> 4) << 2);
#pragma unroll
    for (int ni = 0; ni < 2; ++ni) {
      int c = col0 + wc + (ni << 4) + (lane & 15);
      float bv = (bias && c < N) ? bias[c] : 0.f;
#pragma unroll
      for (int j = 0; j < 4; ++j) {
        int r = rb + j;
        if (r < M && c < N) {
          float v = acc[mi][ni][j] + bv;
          if (c_bf16) ((u16*)Cv)[(size_t)bz * sCb + (size_t)r * ldc + c] = f2b(v);
          else ((float*)Cv)[(size_t)bz * sCb + (size_t)r * ldc + c] = v;
        }
      }
    }
  }
}

// ---------------- window attention via MFMA: 1 block per window, wave = head group ----------------
__global__ __launch_bounds__(256, 2) void win_attn_mfma(const u16* __restrict__ qkv, u16* __restrict__ oat)
{
  __shared__ __align__(16) u16 Pl[4][64 * 72];
  __shared__ __align__(16) u16 Vtl[4][32 * 72];
  int tid = threadIdx.x;
  int wid = tid >> 6, lane = tid & 63;
  int lm = lane & 15, lg = lane >> 4;
  int w = blockIdx.x;
  int b = w >> 8, wh = (w >> 4) & 15, ww = w & 15;
  int rowbase = (wh * 7) * 112 + ww * 7;
  u16* P = Pl[wid];
  u16* Vt = Vtl[wid];
  const u16* base = qkv + (size_t)b * 12544 * 1536;
  u16* ob = oat + (size_t)b * 12544 * 512;
  const float scale = 0.17677669529663687f;

  for (int hh = 0; hh < 4; ++hh) {
    int h = wid * 4 + hh;
    bf16x8 Qf[4], Kf[4];
#pragma unroll
    for (int mi = 0; mi < 4; ++mi) {
      int i = mi * 16 + lm; i = i < 49 ? i : 48;
      int q7 = (i * 147) >> 10;
      int n = rowbase + q7 * 112 + (i - q7 * 7);
      const u16* rp = base + (size_t)n * 1536 + h * 32 + lg * 8;
      Qf[mi] = *(const bf16x8*)(rp);
      Kf[mi] = *(const bf16x8*)(rp + 512);
    }
    {
      int j = lane;
      if (j < 49) {
        int q7 = (j * 147) >> 10;
        int n = rowbase + q7 * 112 + (j - q7 * 7);
        const uint4* vp = (const uint4*)(base + (size_t)n * 1536 + 1024 + h * 32);
#pragma unroll
        for (int t = 0; t < 4; ++t) {
          uint4 u = vp[t];
          Vt[(t * 8 + 0) * 72 + j] = (u16)(u.x & 0xffff); Vt[(t * 8 + 1) * 72 + j] = (u16)(u.x >> 16);
          Vt[(t * 8 + 2) * 72 + j] = (u16)(u.y & 0xffff); Vt[(t * 8 + 3) * 72 + j] = (u16)(u.y >> 16);
          Vt[(t * 8 + 4) * 72 + j] = (u16)(u.z & 0xffff); Vt[(t * 8 + 5) * 72 + j] = (u16)(u.z >> 16);
          Vt[(t * 8 + 6) * 72 + j] = (u16)(u.w & 0xffff); Vt[(t * 8 + 7) * 72 + j] = (u16)(u.w >> 16);
        }
      } else {
#pragma unroll
        for (int d = 0; d < 32; ++d) Vt[d * 72 + j] = 0;
      }
    }
    f32x4 S[4][4];
#pragma unroll
    for (int mi = 0; mi < 4; ++mi)
#pragma unroll
      for (int nj = 0; nj < 4; ++nj) { f32x4 z = {0.f, 0.f, 0.f, 0.f}; S[mi][nj] = z; }
#pragma unroll
    for (int mi = 0; mi < 4; ++mi)
#pragma unroll
      for (int nj = 0; nj < 4; ++nj)
        S[mi][nj] = __builtin_amdgcn_mfma_f32_16x16x32_bf16(Qf[mi], Kf[nj], S[mi][nj], 0, 0, 0);
    float invv[4][4];
#pragma unroll
    for (int mi = 0; mi < 4; ++mi) {
#pragma unroll
      for (int reg = 0; reg < 4; ++reg) {
        float v0 = S[mi][0][reg], v1 = S[mi][1][reg], v2 = S[mi][2][reg], v3 = S[mi][3][reg];
        if (lm) v3 = -1e30f;
        float m = fmaxf(fmaxf(v0, v1), fmaxf(v2, v3));
#pragma unroll
        for (int o = 1; o < 16; o <<= 1) m = fmaxf(m, __shfl_xor(m, o));
        float e0 = __expf((v0 - m) * scale);
        float e1 = __expf((v1 - m) * scale);
        float e2 = __expf((v2 - m) * scale);
        float e3 = lm ? 0.f : __expf((v3 - m) * scale);
        float s = e0 + e1 + e2 + e3;
#pragma unroll
        for (int o = 1; o < 16; o <<= 1) s += __shfl_xor(s, o);
        invv[mi][reg] = 1.f / s;
        int r = mi * 16 + lg * 4 + reg;
        P[r * 72 + lm] = f2b(e0);
        P[r * 72 + 16 + lm] = f2b(e1);
        P[r * 72 + 32 + lm] = f2b(e2);
        P[r * 72 + 48 + lm] = f2b(e3);
      }
    }
    bf16x8 Vf[2][2];
#pragma unroll
    for (int dt = 0; dt < 2; ++dt) {
      Vf[dt][0] = *(const bf16x8*)(Vt + (dt * 16 + lm) * 72 + lg * 8);
      Vf[dt][1] = *(const bf16x8*)(Vt + (dt * 16 + lm) * 72 + 32 + lg * 8);
    }
    f32x4 O[4][2];
#pragma unroll
    for (int mi = 0; mi < 4; ++mi)
#pragma unroll
      for (int dt = 0; dt < 2; ++dt) { f32x4 z = {0.f, 0.f, 0.f, 0.f}; O[mi][dt] = z; }
#pragma unroll
    for (int mi = 0; mi < 4; ++mi) {
      bf16x8 Pf0 = *(const bf16x8*)(P + (mi * 16 + lm) * 72 + lg * 8);
      bf16x8 Pf1 = *(const bf16x8*)(P + (mi * 16 + lm) * 72 + 32 + lg * 8);
#pragma unroll
      for (int dt = 0; dt < 2; ++dt) {
        O[mi][dt] = __builtin_amdgcn_mfma_f32_16x16x32_bf16(Pf0, Vf[dt][0], O[mi][dt], 0, 0, 0);
        O[mi][dt] = __builtin_amdgcn_mfma_f32_16x16x32_bf16(Pf1, Vf[dt][1], O[mi][dt], 0, 0, 0);
      }
    }
#pragma unroll
    for (int mi = 0; mi < 4; ++mi)
#pragma unroll
      for (int reg = 0; reg < 4; ++reg) {
        int i = mi * 16 + lg * 4 + reg;
        if (i < 49) {
          int q7 = (i * 147) >> 10;
          int n = rowbase + q7 * 112 + (i - q7 * 7);
          float iv = invv[mi][reg];
          u16* op = ob + (size_t)n * 512 + h * 32 + lm;
          op[0] = f2b(O[mi][0][reg] * iv);
          op[16] = f2b(O[mi][1][reg] * iv);
        }
      }
  }
}

// ---------------- DCT of 8x8 patches at subsampled positions -> F2 (3136 x 192) bf16 ----------------
__global__ __launch_bounds__(192) void dct_f2(const float* __restrict__ patches, u16* __restrict__ F2)
{
  __shared__ float pv[192];
  __shared__ float Bm[64];
  int blk = blockIdx.x;
  int b = blk / 784, rem = blk % 784;
  int n = ((rem / 28) * 4) * 112 + (rem % 28) * 4;
  int t = threadIdx.x;
  if (t < 64) {
    int k = t >> 3, ii = t & 7;
    float v = cosf(3.14159265358979323846f * (ii + 0.5f) * (float)k * 0.125f) * 0.5f;
    if (k == 0) v *= 0.70710678118654752f;
    Bm[t] = v;
  }
  pv[t] = patches[((size_t)b * 192 + t) * 12544 + n];
  __syncthreads();
  int c = t >> 6, fi = (t >> 3) & 7, fk = t & 7;
  float acc = 0.f;
#pragma unroll
  for (int mm = 0; mm < 8; ++mm) {
    float g = 0.f;
#pragma unroll
    for (int jj = 0; jj < 8; ++jj) g += pv[c * 64 + mm * 8 + jj] * Bm[jj * 8 + fk];
    acc += Bm[fi * 8 + mm] * g;
  }
  F2[(size_t)blk * 192 + t] = f2b(acc);
}

// ---------------- spectral softmax: 1 block per row, 784 cols -> bf16 P (padded to 832) ----------------
__global__ __launch_bounds__(256) void spec_softmax(const float* __restrict__ S, u16* __restrict__ P)
{
  __shared__ float red[4];
  int row = blockIdx.x;
  const float* sr = S + (size_t)row * 784;
  u16* pr = P + (size_t)row * 832;
  int t = threadIdx.x;
  int lane = t & 63, wid = t >> 6;
  float v0 = sr[t];
  float v1 = sr[t + 256];
  float v2 = (t < 272) ? sr[t + 512] : -1e30f;
  float m = fmaxf(fmaxf(v0, v1), v2);
#pragma unroll
  for (int ofs = 32; ofs > 0; ofs >>= 1) m = fmaxf(m, __shfl_xor(m, ofs));
  if (lane == 0) red[wid] = m;
  __syncthreads();
  m = fmaxf(fmaxf(red[0], red[1]), fmaxf(red[2], red[3]));
  __syncthreads();
  const float scale = 0.044194173824159216f;
  float e0 = __expf((v0 - m) * scale);
  float e1 = __expf((v1 - m) * scale);
  float e2 = (t < 272) ? __expf((v2 - m) * scale) : 0.f;
  float sum = e0 + e1 + e2;
#pragma unroll
  for (int ofs = 32; ofs > 0; ofs >>= 1) sum += __shfl_xor(sum, ofs);
  if (lane == 0) red[wid] = sum;
  __syncthreads();
  sum = red[0] + red[1] + red[2] + red[3];
  float inv = 1.f / sum;
  pr[t] = f2b(e0 * inv);
  pr[t + 256] = f2b(e1 * inv);
  if (t < 272) pr[t + 512] = f2b(e2 * inv);
  else if (t < 320) pr[t + 512] = 0;
}

// ---------------- V transpose for PV gemm: Vt[b][n][k] = V[b][k][n], k padded to 832 ----------------
__global__ __launch_bounds__(256) void transV(const u16* __restrict__ qkvs, u16* __restrict__ Vt)
{
  int idx = blockIdx.x * 256 + threadIdx.x;
  int k = idx % 832;
  int rest = idx / 832;
  int n = rest % 512, b = rest / 512;
  u16 v = 0;
  if (k < 784) v = qkvs[((size_t)(b * 784 + k)) * 1536 + 1024 + n];
  Vt[idx] = v;
}

// ---------------- combine + nearest-upsample gather + LayerNorm ----------------
__global__ __launch_bounds__(256) void combine_ln(
    const float* __restrict__ tokens, const u16* __restrict__ sp,
    const float* __restrict__ so, const float* __restrict__ alpha,
    float* __restrict__ out)
{
  int nidx = blockIdx.x;
  int b = nidx / 12544, pos = nidx % 12544;
  int i = pos / 112, j = pos % 112;
  const float* tr = tokens + (size_t)nidx * 512;
  const u16* sr = sp + (size_t)nidx * 512;
  const float* qr = so + (size_t)(b * 784 + (i >> 2) * 28 + (j >> 2)) * 512;
  float al = 1.f / (1.f + __expf(-alpha[0]));
  float be = 1.f - al;
  int t = threadIdx.x;
  float x0 = tr[t] + al * b2f(sr[t]) + be * qr[t];
  float x1 = tr[t + 256] + al * b2f(sr[t + 256]) + be * qr[t + 256];
  float s = x0 + x1, ss = x0 * x0 + x1 * x1;
#pragma unroll
  for (int ofs = 32; ofs > 0; ofs >>= 1) { s += __shfl_xor(s, ofs); ss += __shfl_xor(ss, ofs); }
  __shared__ float rs[4], rq[4];
  int lane = t & 63, wid = t >> 6;
  if (lane == 0) { rs[wid] = s; rq[wid] = ss; }
  __syncthreads();
  s = rs[0] + rs[1] + rs[2] + rs[3];
  ss = rq[0] + rq[1] + rq[2] + rq[3];
  float mu = s * 0.001953125f;
  float var = ss * 0.001953125f - mu * mu;
  float rstd = rsqrtf(var + 1e-5f);
  float* orow = out + (size_t)nidx * 512;
  orow[t] = (x0 - mu) * rstd;
  orow[t + 256] = (x1 - mu) * rstd;
}

// ---------------- coalesced tiled transpose: dst[n*K+k] = f2b(src[k*Nc+n]) ----------------
__global__ __launch_bounds__(256) void transT(const float* __restrict__ src, u16* __restrict__ dst, int K, int Nc)
{
  __shared__ float tile[64][65];
  int tk0 = blockIdx.y << 6, tn0 = blockIdx.x << 6;
  int j = threadIdx.x & 63, i4 = threadIdx.x >> 6;
#pragma unroll
  for (int i = i4; i < 64; i += 4) {
    int k = tk0 + i, n = tn0 + j;
    tile[i][j] = (k < K && n < Nc) ? src[(size_t)k * Nc + n] : 0.f;
  }
  __syncthreads();
#pragma unroll
  for (int i = i4; i < 64; i += 4) {
    int n = tn0 + i, k = tk0 + j;
    if (n < Nc && k < K) dst[(size_t)n * K + k] = f2b(tile[j][i]);
  }
}

__global__ __launch_bounds__(256) void cvtbf(const float* __restrict__ src, u16* __restrict__ dst)
{
  size_t i = ((size_t)blockIdx.x * 256 + threadIdx.x) * 4;
  float4 v = *(const float4*)(src + i);
  uint2 u;
  u.x = pack2(v.x, v.y);
  u.y = pack2(v.z, v.w);
  *(uint2*)(dst + i) = u;
}

__global__ __launch_bounds__(256) void stack_bias(
    const float* bq_, const float* bk_, const float* bv_,
    const float* bsq_, const float* bsk_, const float* bsv_,
    float* bqkv, float* bsqkv)
{
  int i = blockIdx.x * 256 + threadIdx.x;
  if (i >= 1536) return;
  int r = i & 511;
  bqkv[i]  = (i < 512) ? bq_[r]  : (i < 1024) ? bk_[r]  : bv_[r];
  bsqkv[i] = (i < 512) ? bsq_[r] : (i < 1024) ? bsk_[r] : bsv_[r];
}

// ---------------- launch ----------------
extern "C" void kernel_launch(void* const* d_in, const int* in_sizes, int n_in,
                              void* d_out, int out_size, void* d_ws, size_t ws_size,
                              hipStream_t stream) {
  (void)in_sizes; (void)n_in; (void)out_size; (void)ws_size;
  const float* tokens = (const float*)d_in[0];
  const float* patches = (const float*)d_in[1];
  const float* Wq  = (const float*)d_in[2];
  const float* bq  = (const float*)d_in[3];
  const float* Wk  = (const float*)d_in[4];
  const float* bk  = (const float*)d_in[5];
  const float* Wv  = (const float*)d_in[6];
  const float* bv  = (const float*)d_in[7];
  const float* Wo  = (const float*)d_in[8];
  const float* bo  = (const float*)d_in[9];
  const float* Wsp = (const float*)d_in[10];
  const float* bsp = (const float*)d_in[11];
  const float* Wsq = (const float*)d_in[12];
  const float* bsq = (const float*)d_in[13];
  const float* Wsk = (const float*)d_in[14];
  const float* bsk = (const float*)d_in[15];
  const float* Wsv = (const float*)d_in[16];
  const float* bsv = (const float*)d_in[17];
  const float* Wso = (const float*)d_in[18];
  const float* bso = (const float*)d_in[19];
  const float* alpha = (const float*)d_in[20];
  float* out = (float*)d_out;

  char* ws = (char*)d_ws;
  u16* tokbf  = (u16*)ws;
  u16* qkv    = (u16*)(ws + 51380224);
  char* pp    = ws + 51380224 + 154140672;
  u16* WqkvT  = (u16*)pp; pp += 1572864;
  u16* WoT    = (u16*)pp; pp += 524288;
  u16* WsqkvT = (u16*)pp; pp += 1572864;
  u16* WsoT   = (u16*)pp; pp += 524288;
  u16* WspT   = (u16*)pp; pp += 196608;
  float* bqkv = (float*)pp; pp += 6144;
  float* bsqkv= (float*)pp; pp += 6144;
  u16* F2b    = (u16*)pp; pp += 1204224;
  u16* sd     = (u16*)pp; pp += 3211264;
  u16* qkvs   = (u16*)pp; pp += 9633792;
  u16* sopre  = (u16*)pp; pp += 3211264;
  float* sofin= (float*)pp; pp += 6422528;

  float* Sbuf = (float*)tokbf;
  u16* Pbuf   = (u16*)(ws + 9834496);
  u16* Vt     = (u16*)(ws + 9834496 + 5218304);

  // prep (coalesced tiled transposes)
  cvtbf<<<25088, 256, 0, stream>>>(tokens, tokbf);
  transT<<<dim3(8, 8), 256, 0, stream>>>(Wq, WqkvT, 512, 512);
  transT<<<dim3(8, 8), 256, 0, stream>>>(Wk, WqkvT + 262144, 512, 512);
  transT<<<dim3(8, 8), 256, 0, stream>>>(Wv, WqkvT + 524288, 512, 512);
  transT<<<dim3(8, 8), 256, 0, stream>>>(Wo, WoT, 512, 512);
  transT<<<dim3(8, 8), 256, 0, stream>>>(Wsq, WsqkvT, 512, 512);
  transT<<<dim3(8, 8), 256, 0, stream>>>(Wsk, WsqkvT + 262144, 512, 512);
  transT<<<dim3(8, 8), 256, 0, stream>>>(Wsv, WsqkvT + 524288, 512, 512);
  transT<<<dim3(8, 8), 256, 0, stream>>>(Wso, WsoT, 512, 512);
  transT<<<dim3(8, 3), 256, 0, stream>>>(Wsp, WspT, 192, 512);
  stack_bias<<<6, 256, 0, stream>>>(bq, bk, bv, bsq, bsk, bsv, bqkv, bsqkv);

  // spatial path: 512-thread shared-tile experiment on the two big GEMMs
  gemm_bt512<<<dim3(12, 392), 512, 0, stream>>>(tokbf, 512, WqkvT, 512, bqkv, qkv, 1536, 50176, 1536, 512, 1);
  win_attn_mfma<<<1024, 256, 0, stream>>>(qkv, tokbf);
  gemm_bt512<<<dim3(4, 392), 512, 0, stream>>>(tokbf, 512, WoT, 512, bo, qkv, 512, 50176, 512, 512, 1);

  // spectral path (proven R9 gemm_bt)
  dct_f2<<<3136, 192, 0, stream>>>(patches, F2b);
  gemm_bt<<<dim3(8, 25), 256, 0, stream>>>(F2b, 192, 0, WspT, 192, 0, bsp, sd, 512, 0, 3136, 512, 192, 1);
  gemm_bt<<<dim3(24, 25), 256, 0, stream>>>(sd, 512, 0, WsqkvT, 512, 0, bsqkv, qkvs, 1536, 0, 3136, 1536, 512, 1);
  gemm_bt<<<dim3(13, 7, 4), 256, 0, stream>>>(qkvs, 1536, (long)784 * 1536, qkvs + 512, 1536, (long)784 * 1536,
                                              nullptr, Sbuf, 784, (long)784 * 784, 784, 784, 512, 0);
  spec_softmax<<<3136, 256, 0, stream>>>(Sbuf, Pbuf);
  transV<<<6656, 256, 0, stream>>>(qkvs, Vt);
  gemm_bt<<<dim3(8, 7, 4), 256, 0, stream>>>(Pbuf, 832, (long)784 * 832, Vt, 832, (long)512 * 832,
                                             nullptr, sopre, 512, (long)784 * 512, 784, 512, 832, 1);
  gemm_bt<<<dim3(8, 25), 256, 0, stream>>>(sopre, 512, 0, WsoT, 512, 0, bso, sofin, 512, 0, 3136, 512, 512, 0);

  // combine + LN
  combine_ln<<<50176, 256, 0, stream>>>(tokens, qkv, sofin, alpha, out);
}

// Round 13
// 513.463 us; speedup vs baseline: 1.5168x; 1.0183x over previous
//
#include <hip/hip_runtime.h>

typedef unsigned short u16;
typedef __attribute__((ext_vector_type(4))) float f32x4;
typedef __attribute__((ext_vector_type(8))) short bf16x8;

#define AS1 __attribute__((address_space(1)))
#define AS3 __attribute__((address_space(3)))
#define GLL(gp, lp) __builtin_amdgcn_global_load_lds((const AS1 void*)(gp), (AS3 void*)(lp), 16, 0, 0)

__device__ __forceinline__ float b2f(u16 v) { return __uint_as_float(((unsigned)v) << 16); }
__device__ __forceinline__ u16 f2b(float f) {
  unsigned u = __float_as_uint(f);
  u += 0x7fffu + ((u >> 16) & 1u);
  return (u16)(u >> 16);
}
__device__ __forceinline__ unsigned pack2(float a, float b) {
  return (unsigned)f2b(a) | ((unsigned)f2b(b) << 16);
}
__device__ __forceinline__ float blo(unsigned u) { return __uint_as_float(u << 16); }
__device__ __forceinline__ float bhi(unsigned u) { return __uint_as_float(u & 0xffff0000u); }

// ---------------- 512-thread 128x128-tile GEMM: QKV only (proven R12, 131.5us) ----------------
__global__ __launch_bounds__(512, 6) void gemm_bt512(
    const u16* __restrict__ A, int lda,
    const u16* __restrict__ Bt, int ldb,
    const float* __restrict__ bias, void* __restrict__ Cv, int ldc,
    int M, int N, int K, int c_bf16)
{
  __shared__ __align__(16) u16 ldsA[128 * 64];
  __shared__ __align__(16) u16 ldsB[128 * 64];
  int tid = threadIdx.x;
  int wid = tid >> 6, lane = tid & 63;
  int lm = lane & 15, lg = lane >> 4;
  int wm = wid >> 2, wn = wid & 3;

  int nbx = gridDim.x;
  int lin = blockIdx.y * nbx + blockIdx.x;
  int nwg = nbx * gridDim.y;
  int qc = nwg >> 3, rc = nwg & 7;
  int xcd = lin & 7, pos = lin >> 3;
  int nlin = (xcd < rc ? xcd * (qc + 1) : rc * (qc + 1) + (xcd - rc) * qc) + pos;
  int bx = nlin % nbx, by = nlin / nbx;

  int row0 = by << 7;
  int col0 = bx << 7;
  int wr = wm << 6, wc = wn << 5;

  const u16* pA[2];
  const u16* pB[2];
  int ldso[2];
#pragma unroll
  for (int q = 0; q < 2; ++q) {
    int o = (q << 13) + (tid << 4);
    int r = o >> 7;
    int cs = (o >> 4) & 7;
    int cl = cs ^ (r & 7);
    int ar = row0 + r; ar = ar < M ? ar : M - 1;
    int br = col0 + r; br = br < N ? br : N - 1;
    pA[q] = A + (size_t)ar * lda + (cl << 3);
    pB[q] = Bt + (size_t)br * ldb + (cl << 3);
    ldso[q] = o >> 1;
  }

  f32x4 acc[4][2];
#pragma unroll
  for (int i = 0; i < 4; ++i)
#pragma unroll
    for (int j = 0; j < 2; ++j) { f32x4 z = {0.f, 0.f, 0.f, 0.f}; acc[i][j] = z; }

  int nt = K >> 6;
  for (int t = 0; t < nt; ++t) {
#pragma unroll
    for (int q = 0; q < 2; ++q) {
      GLL(pA[q], ldsA + ldso[q]);
      GLL(pB[q], ldsB + ldso[q]);
      pA[q] += 64; pB[q] += 64;
    }
    __syncthreads();
#pragma unroll
    for (int kk = 0; kk < 2; ++kk) {
      bf16x8 af[4], bg[2];
#pragma unroll
      for (int mi = 0; mi < 4; ++mi) {
        int r = wr + (mi << 4) + lm;
        int cs = ((kk << 2) + lg) ^ (r & 7);
        af[mi] = *(const bf16x8*)(ldsA + (r << 6) + (cs << 3));
      }
#pragma unroll
      for (int ni = 0; ni < 2; ++ni) {
        int r = wc + (ni << 4) + lm;
        int cs = ((kk << 2) + lg) ^ (r & 7);
        bg[ni] = *(const bf16x8*)(ldsB + (r << 6) + (cs << 3));
      }
#pragma unroll
      for (int mi = 0; mi < 4; ++mi)
#pragma unroll
        for (int ni = 0; ni < 2; ++ni)
          acc[mi][ni] = __builtin_amdgcn_mfma_f32_16x16x32_bf16(af[mi], bg[ni], acc[mi][ni], 0, 0, 0);
    }
    __syncthreads();
  }

#pragma unroll
  for (int mi = 0; mi < 4; ++mi) {
    int rb = row0 + wr + (mi << 4) + (lg << 2);
#pragma unroll
    for (int ni = 0; ni < 2; ++ni) {
      int c = col0 + wc + (ni << 4) + lm;
      float bv = (bias && c < N) ? bias[c] : 0.f;
#pragma unroll
      for (int j = 0; j < 4; ++j) {
        int r = rb + j;
        if (r < M && c < N) {
          float v = acc[mi][ni][j] + bv;
          if (c_bf16) ((u16*)Cv)[(size_t)r * ldc + c] = f2b(v);
          else ((float*)Cv)[(size_t)r * ldc + c] = v;
        }
      }
    }
  }
}

// ---------------- 128x64-tile GEMM (R9, proven): O-proj + batched / odd shapes ----------------
__global__ __launch_bounds__(256, 6) void gemm_bt(
    const u16* __restrict__ A, int lda, long sAb,
    const u16* __restrict__ Bt, int ldb, long sBb,
    const float* __restrict__ bias, void* __restrict__ Cv, int ldc, long sCb,
    int M, int N, int K, int c_bf16)
{
  __shared__ __align__(16) u16 ldsA[128 * 64];
  __shared__ __align__(16) u16 ldsB[64 * 64];
  int tid = threadIdx.x;
  int wid = tid >> 6, lane = tid & 63;

  int nbx = gridDim.x;
  int lin = blockIdx.y * nbx + blockIdx.x;
  int nwg = nbx * gridDim.y;
  int qc = nwg >> 3, rc = nwg & 7;
  int xcd = lin & 7, pos = lin >> 3;
  int nlin = (xcd < rc ? xcd * (qc + 1) : rc * (qc + 1) + (xcd - rc) * qc) + pos;
  int bx = nlin % nbx, by = nlin / nbx;

  int row0 = by << 7;
  int col0 = bx << 6;
  int bz = blockIdx.z;
  A += (size_t)bz * sAb;
  Bt += (size_t)bz * sBb;
  int wr = (wid >> 1) << 6, wc = (wid & 1) << 5;

  const u16* pA[4];
  const u16* pB[2];
  int ldsoA[4], ldsoB[2];
#pragma unroll
  for (int q = 0; q < 4; ++q) {
    int inst = (wid << 2) + q;
    int o = (inst << 10) + (lane << 4);
    int r = o >> 7;
    int cs = (o >> 4) & 7;
    int cl = cs ^ (r & 7);
    int ar = row0 + r; ar = ar < M ? ar : M - 1;
    pA[q] = A + (size_t)ar * lda + (cl << 3);
    ldsoA[q] = inst << 9;
  }
#pragma unroll
  for (int q = 0; q < 2; ++q) {
    int inst = (wid << 1) + q;
    int o = (inst << 10) + (lane << 4);
    int r = o >> 7;
    int cs = (o >> 4) & 7;
    int cl = cs ^ (r & 7);
    int br = col0 + r; br = br < N ? br : N - 1;
    pB[q] = Bt + (size_t)br * ldb + (cl << 3);
    ldsoB[q] = inst << 9;
  }

  f32x4 acc[4][2];
#pragma unroll
  for (int i = 0; i < 4; ++i)
#pragma unroll
    for (int j = 0; j < 2; ++j) { f32x4 z = {0.f, 0.f, 0.f, 0.f}; acc[i][j] = z; }

  int nt = K >> 6;
  for (int t = 0; t < nt; ++t) {
#pragma unroll
    for (int q = 0; q < 4; ++q) { GLL(pA[q], ldsA + ldsoA[q]); pA[q] += 64; }
#pragma unroll
    for (int q = 0; q < 2; ++q) { GLL(pB[q], ldsB + ldsoB[q]); pB[q] += 64; }
    __syncthreads();
#pragma unroll
    for (int kk = 0; kk < 2; ++kk) {
      bf16x8 af[4], bg[2];
#pragma unroll
      for (int mi = 0; mi < 4; ++mi) {
        int r = wr + (mi << 4) + (lane & 15);
        int cs = ((kk << 2) + (lane >> 4)) ^ (r & 7);
        af[mi] = *(const bf16x8*)(ldsA + (r << 6) + (cs << 3));
      }
#pragma unroll
      for (int ni = 0; ni < 2; ++ni) {
        int r = wc + (ni << 4) + (lane & 15);
        int cs = ((kk << 2) + (lane >> 4)) ^ (r & 7);
        bg[ni] = *(const bf16x8*)(ldsB + (r << 6) + (cs << 3));
      }
#pragma unroll
      for (int mi = 0; mi < 4; ++mi)
#pragma unroll
        for (int ni = 0; ni < 2; ++ni)
          acc[mi][ni] = __builtin_amdgcn_mfma_f32_16x16x32_bf16(af[mi], bg[ni], acc[mi][ni], 0, 0, 0);
    }
    __syncthreads();
  }

#pragma unroll
  for (int mi = 0; mi < 4; ++mi) {
    int rb = row0 + wr + (mi << 4) + ((lane >> 4) << 2);
#pragma unroll
    for (int ni = 0; ni < 2; ++ni) {
      int c = col0 + wc + (ni << 4) + (lane & 15);
      float bv = (bias && c < N) ? bias[c] : 0.f;
#pragma unroll
      for (int j = 0; j < 4; ++j) {
        int r = rb + j;
        if (r < M && c < N) {
          float v = acc[mi][ni][j] + bv;
          if (c_bf16) ((u16*)Cv)[(size_t)bz * sCb + (size_t)r * ldc + c] = f2b(v);
          else ((float*)Cv)[(size_t)bz * sCb + (size_t)r * ldc + c] = v;
        }
      }
    }
  }
}

// ---------------- window attention via MFMA: 1 block per window, wave = head group ----------------
__global__ __launch_bounds__(256, 2) void win_attn_mfma(const u16* __restrict__ qkv, u16* __restrict__ oat)
{
  __shared__ __align__(16) u16 Pl[4][64 * 72];
  __shared__ __align__(16) u16 Vtl[4][32 * 72];
  int tid = threadIdx.x;
  int wid = tid >> 6, lane = tid & 63;
  int lm = lane & 15, lg = lane >> 4;
  int w = blockIdx.x;
  int b = w >> 8, wh = (w >> 4) & 15, ww = w & 15;
  int rowbase = (wh * 7) * 112 + ww * 7;
  u16* P = Pl[wid];
  u16* Vt = Vtl[wid];
  const u16* base = qkv + (size_t)b * 12544 * 1536;
  u16* ob = oat + (size_t)b * 12544 * 512;
  const float scale = 0.17677669529663687f;

  for (int hh = 0; hh < 4; ++hh) {
    int h = wid * 4 + hh;
    bf16x8 Qf[4], Kf[4];
#pragma unroll
    for (int mi = 0; mi < 4; ++mi) {
      int i = mi * 16 + lm; i = i < 49 ? i : 48;
      int q7 = (i * 147) >> 10;
      int n = rowbase + q7 * 112 + (i - q7 * 7);
      const u16* rp = base + (size_t)n * 1536 + h * 32 + lg * 8;
      Qf[mi] = *(const bf16x8*)(rp);
      Kf[mi] = *(const bf16x8*)(rp + 512);
    }
    {
      int j = lane;
      if (j < 49) {
        int q7 = (j * 147) >> 10;
        int n = rowbase + q7 * 112 + (j - q7 * 7);
        const uint4* vp = (const uint4*)(base + (size_t)n * 1536 + 1024 + h * 32);
#pragma unroll
        for (int t = 0; t < 4; ++t) {
          uint4 u = vp[t];
          Vt[(t * 8 + 0) * 72 + j] = (u16)(u.x & 0xffff); Vt[(t * 8 + 1) * 72 + j] = (u16)(u.x >> 16);
          Vt[(t * 8 + 2) * 72 + j] = (u16)(u.y & 0xffff); Vt[(t * 8 + 3) * 72 + j] = (u16)(u.y >> 16);
          Vt[(t * 8 + 4) * 72 + j] = (u16)(u.z & 0xffff); Vt[(t * 8 + 5) * 72 + j] = (u16)(u.z >> 16);
          Vt[(t * 8 + 6) * 72 + j] = (u16)(u.w & 0xffff); Vt[(t * 8 + 7) * 72 + j] = (u16)(u.w >> 16);
        }
      } else {
#pragma unroll
        for (int d = 0; d < 32; ++d) Vt[d * 72 + j] = 0;
      }
    }
    f32x4 S[4][4];
#pragma unroll
    for (int mi = 0; mi < 4; ++mi)
#pragma unroll
      for (int nj = 0; nj < 4; ++nj) { f32x4 z = {0.f, 0.f, 0.f, 0.f}; S[mi][nj] = z; }
#pragma unroll
    for (int mi = 0; mi < 4; ++mi)
#pragma unroll
      for (int nj = 0; nj < 4; ++nj)
        S[mi][nj] = __builtin_amdgcn_mfma_f32_16x16x32_bf16(Qf[mi], Kf[nj], S[mi][nj], 0, 0, 0);
    float invv[4][4];
#pragma unroll
    for (int mi = 0; mi < 4; ++mi) {
#pragma unroll
      for (int reg = 0; reg < 4; ++reg) {
        float v0 = S[mi][0][reg], v1 = S[mi][1][reg], v2 = S[mi][2][reg], v3 = S[mi][3][reg];
        if (lm) v3 = -1e30f;
        float m = fmaxf(fmaxf(v0, v1), fmaxf(v2, v3));
#pragma unroll
        for (int o = 1; o < 16; o <<= 1) m = fmaxf(m, __shfl_xor(m, o));
        float e0 = __expf((v0 - m) * scale);
        float e1 = __expf((v1 - m) * scale);
        float e2 = __expf((v2 - m) * scale);
        float e3 = lm ? 0.f : __expf((v3 - m) * scale);
        float s = e0 + e1 + e2 + e3;
#pragma unroll
        for (int o = 1; o < 16; o <<= 1) s += __shfl_xor(s, o);
        invv[mi][reg] = 1.f / s;
        int r = mi * 16 + lg * 4 + reg;
        P[r * 72 + lm] = f2b(e0);
        P[r * 72 + 16 + lm] = f2b(e1);
        P[r * 72 + 32 + lm] = f2b(e2);
        P[r * 72 + 48 + lm] = f2b(e3);
      }
    }
    bf16x8 Vf[2][2];
#pragma unroll
    for (int dt = 0; dt < 2; ++dt) {
      Vf[dt][0] = *(const bf16x8*)(Vt + (dt * 16 + lm) * 72 + lg * 8);
      Vf[dt][1] = *(const bf16x8*)(Vt + (dt * 16 + lm) * 72 + 32 + lg * 8);
    }
    f32x4 O[4][2];
#pragma unroll
    for (int mi = 0; mi < 4; ++mi)
#pragma unroll
      for (int dt = 0; dt < 2; ++dt) { f32x4 z = {0.f, 0.f, 0.f, 0.f}; O[mi][dt] = z; }
#pragma unroll
    for (int mi = 0; mi < 4; ++mi) {
      bf16x8 Pf0 = *(const bf16x8*)(P + (mi * 16 + lm) * 72 + lg * 8);
      bf16x8 Pf1 = *(const bf16x8*)(P + (mi * 16 + lm) * 72 + 32 + lg * 8);
#pragma unroll
      for (int dt = 0; dt < 2; ++dt) {
        O[mi][dt] = __builtin_amdgcn_mfma_f32_16x16x32_bf16(Pf0, Vf[dt][0], O[mi][dt], 0, 0, 0);
        O[mi][dt] = __builtin_amdgcn_mfma_f32_16x16x32_bf16(Pf1, Vf[dt][1], O[mi][dt], 0, 0, 0);
      }
    }
#pragma unroll
    for (int mi = 0; mi < 4; ++mi)
#pragma unroll
      for (int reg = 0; reg < 4; ++reg) {
        int i = mi * 16 + lg * 4 + reg;
        if (i < 49) {
          int q7 = (i * 147) >> 10;
          int n = rowbase + q7 * 112 + (i - q7 * 7);
          float iv = invv[mi][reg];
          u16* op = ob + (size_t)n * 512 + h * 32 + lm;
          op[0] = f2b(O[mi][0][reg] * iv);
          op[16] = f2b(O[mi][1][reg] * iv);
        }
      }
  }
}

// ---------------- DCT of 8x8 patches at subsampled positions -> F2 (3136 x 192) bf16 ----------------
__global__ __launch_bounds__(192) void dct_f2(const float* __restrict__ patches, u16* __restrict__ F2)
{
  __shared__ float pv[192];
  __shared__ float Bm[64];
  int blk = blockIdx.x;
  int b = blk / 784, rem = blk % 784;
  int n = ((rem / 28) * 4) * 112 + (rem % 28) * 4;
  int t = threadIdx.x;
  if (t < 64) {
    int k = t >> 3, ii = t & 7;
    float v = cosf(3.14159265358979323846f * (ii + 0.5f) * (float)k * 0.125f) * 0.5f;
    if (k == 0) v *= 0.70710678118654752f;
    Bm[t] = v;
  }
  pv[t] = patches[((size_t)b * 192 + t) * 12544 + n];
  __syncthreads();
  int c = t >> 6, fi = (t >> 3) & 7, fk = t & 7;
  float acc = 0.f;
#pragma unroll
  for (int mm = 0; mm < 8; ++mm) {
    float g = 0.f;
#pragma unroll
    for (int jj = 0; jj < 8; ++jj) g += pv[c * 64 + mm * 8 + jj] * Bm[jj * 8 + fk];
    acc += Bm[fi * 8 + mm] * g;
  }
  F2[(size_t)blk * 192 + t] = f2b(acc);
}

// ---------------- spectral softmax: 1 block per row, 784 cols -> bf16 P (padded to 832) ----------------
__global__ __launch_bounds__(256) void spec_softmax(const float* __restrict__ S, u16* __restrict__ P)
{
  __shared__ float red[4];
  int row = blockIdx.x;
  const float* sr = S + (size_t)row * 784;
  u16* pr = P + (size_t)row * 832;
  int t = threadIdx.x;
  int lane = t & 63, wid = t >> 6;
  float v0 = sr[t];
  float v1 = sr[t + 256];
  float v2 = (t < 272) ? sr[t + 512] : -1e30f;
  float m = fmaxf(fmaxf(v0, v1), v2);
#pragma unroll
  for (int ofs = 32; ofs > 0; ofs >>= 1) m = fmaxf(m, __shfl_xor(m, ofs));
  if (lane == 0) red[wid] = m;
  __syncthreads();
  m = fmaxf(fmaxf(red[0], red[1]), fmaxf(red[2], red[3]));
  __syncthreads();
  const float scale = 0.044194173824159216f;
  float e0 = __expf((v0 - m) * scale);
  float e1 = __expf((v1 - m) * scale);
  float e2 = (t < 272) ? __expf((v2 - m) * scale) : 0.f;
  float sum = e0 + e1 + e2;
#pragma unroll
  for (int ofs = 32; ofs > 0; ofs >>= 1) sum += __shfl_xor(sum, ofs);
  if (lane == 0) red[wid] = sum;
  __syncthreads();
  sum = red[0] + red[1] + red[2] + red[3];
  float inv = 1.f / sum;
  pr[t] = f2b(e0 * inv);
  pr[t + 256] = f2b(e1 * inv);
  if (t < 272) pr[t + 512] = f2b(e2 * inv);
  else if (t < 320) pr[t + 512] = 0;
}

// ---------------- V transpose for PV gemm: Vt[b][n][k] = V[b][k][n], k padded to 832 ----------------
__global__ __launch_bounds__(256) void transV(const u16* __restrict__ qkvs, u16* __restrict__ Vt)
{
  int idx = blockIdx.x * 256 + threadIdx.x;
  int k = idx % 832;
  int rest = idx / 832;
  int n = rest % 512, b = rest / 512;
  u16 v = 0;
  if (k < 784) v = qkvs[((size_t)(b * 784 + k)) * 1536 + 1024 + n];
  Vt[idx] = v;
}

// ---------------- combine + nearest-upsample gather + LayerNorm ----------------
__global__ __launch_bounds__(256) void combine_ln(
    const float* __restrict__ tokens, const u16* __restrict__ sp,
    const float* __restrict__ so, const float* __restrict__ alpha,
    float* __restrict__ out)
{
  int nidx = blockIdx.x;
  int b = nidx / 12544, pos = nidx % 12544;
  int i = pos / 112, j = pos % 112;
  const float* tr = tokens + (size_t)nidx * 512;
  const u16* sr = sp + (size_t)nidx * 512;
  const float* qr = so + (size_t)(b * 784 + (i >> 2) * 28 + (j >> 2)) * 512;
  float al = 1.f / (1.f + __expf(-alpha[0]));
  float be = 1.f - al;
  int t = threadIdx.x;
  float x0 = tr[t] + al * b2f(sr[t]) + be * qr[t];
  float x1 = tr[t + 256] + al * b2f(sr[t + 256]) + be * qr[t + 256];
  float s = x0 + x1, ss = x0 * x0 + x1 * x1;
#pragma unroll
  for (int ofs = 32; ofs > 0; ofs >>= 1) { s += __shfl_xor(s, ofs); ss += __shfl_xor(ss, ofs); }
  __shared__ float rs[4], rq[4];
  int lane = t & 63, wid = t >> 6;
  if (lane == 0) { rs[wid] = s; rq[wid] = ss; }
  __syncthreads();
  s = rs[0] + rs[1] + rs[2] + rs[3];
  ss = rq[0] + rq[1] + rq[2] + rq[3];
  float mu = s * 0.001953125f;
  float var = ss * 0.001953125f - mu * mu;
  float rstd = rsqrtf(var + 1e-5f);
  float* orow = out + (size_t)nidx * 512;
  orow[t] = (x0 - mu) * rstd;
  orow[t + 256] = (x1 - mu) * rstd;
}

// ---------------- coalesced tiled transpose: dst[n*K+k] = f2b(src[k*Nc+n]) ----------------
__global__ __launch_bounds__(256) void transT(const float* __restrict__ src, u16* __restrict__ dst, int K, int Nc)
{
  __shared__ float tile[64][65];
  int tk0 = blockIdx.y << 6, tn0 = blockIdx.x << 6;
  int j = threadIdx.x & 63, i4 = threadIdx.x >> 6;
#pragma unroll
  for (int i = i4; i < 64; i += 4) {
    int k = tk0 + i, n = tn0 + j;
    tile[i][j] = (k < K && n < Nc) ? src[(size_t)k * Nc + n] : 0.f;
  }
  __syncthreads();
#pragma unroll
  for (int i = i4; i < 64; i += 4) {
    int n = tn0 + i, k = tk0 + j;
    if (n < Nc && k < K) dst[(size_t)n * K + k] = f2b(tile[j][i]);
  }
}

__global__ __launch_bounds__(256) void cvtbf(const float* __restrict__ src, u16* __restrict__ dst)
{
  size_t i = ((size_t)blockIdx.x * 256 + threadIdx.x) * 4;
  float4 v = *(const float4*)(src + i);
  uint2 u;
  u.x = pack2(v.x, v.y);
  u.y = pack2(v.z, v.w);
  *(uint2*)(dst + i) = u;
}

__global__ __launch_bounds__(256) void stack_bias(
    const float* bq_, const float* bk_, const float* bv_,
    const float* bsq_, const float* bsk_, const float* bsv_,
    float* bqkv, float* bsqkv)
{
  int i = blockIdx.x * 256 + threadIdx.x;
  if (i >= 1536) return;
  int r = i & 511;
  bqkv[i]  = (i < 512) ? bq_[r]  : (i < 1024) ? bk_[r]  : bv_[r];
  bsqkv[i] = (i < 512) ? bsq_[r] : (i < 1024) ? bsk_[r] : bsv_[r];
}

// ---------------- launch ----------------
extern "C" void kernel_launch(void* const* d_in, const int* in_sizes, int n_in,
                              void* d_out, int out_size, void* d_ws, size_t ws_size,
                              hipStream_t stream) {
  (void)in_sizes; (void)n_in; (void)out_size; (void)ws_size;
  const float* tokens = (const float*)d_in[0];
  const float* patches = (const float*)d_in[1];
  const float* Wq  = (const float*)d_in[2];
  const float* bq  = (const float*)d_in[3];
  const float* Wk  = (const float*)d_in[4];
  const float* bk  = (const float*)d_in[5];
  const float* Wv  = (const float*)d_in[6];
  const float* bv  = (const float*)d_in[7];
  const float* Wo  = (const float*)d_in[8];
  const float* bo  = (const float*)d_in[9];
  const float* Wsp = (const float*)d_in[10];
  const float* bsp = (const float*)d_in[11];
  const float* Wsq = (const float*)d_in[12];
  const float* bsq = (const float*)d_in[13];
  const float* Wsk = (const float*)d_in[14];
  const float* bsk = (const float*)d_in[15];
  const float* Wsv = (const float*)d_in[16];
  const float* bsv = (const float*)d_in[17];
  const float* Wso = (const float*)d_in[18];
  const float* bso = (const float*)d_in[19];
  const float* alpha = (const float*)d_in[20];
  float* out = (float*)d_out;

  char* ws = (char*)d_ws;
  u16* tokbf  = (u16*)ws;
  u16* qkv    = (u16*)(ws + 51380224);
  char* pp    = ws + 51380224 + 154140672;
  u16* WqkvT  = (u16*)pp; pp += 1572864;
  u16* WoT    = (u16*)pp; pp += 524288;
  u16* WsqkvT = (u16*)pp; pp += 1572864;
  u16* WsoT   = (u16*)pp; pp += 524288;
  u16* WspT   = (u16*)pp; pp += 196608;
  float* bqkv = (float*)pp; pp += 6144;
  float* bsqkv= (float*)pp; pp += 6144;
  u16* F2b    = (u16*)pp; pp += 1204224;
  u16* sd     = (u16*)pp; pp += 3211264;
  u16* qkvs   = (u16*)pp; pp += 9633792;
  u16* sopre  = (u16*)pp; pp += 3211264;
  float* sofin= (float*)pp; pp += 6422528;

  float* Sbuf = (float*)tokbf;
  u16* Pbuf   = (u16*)(ws + 9834496);
  u16* Vt     = (u16*)(ws + 9834496 + 5218304);

  // prep (coalesced tiled transposes)
  cvtbf<<<25088, 256, 0, stream>>>(tokens, tokbf);
  transT<<<dim3(8, 8), 256, 0, stream>>>(Wq, WqkvT, 512, 512);
  transT<<<dim3(8, 8), 256, 0, stream>>>(Wk, WqkvT + 262144, 512, 512);
  transT<<<dim3(8, 8), 256, 0, stream>>>(Wv, WqkvT + 524288, 512, 512);
  transT<<<dim3(8, 8), 256, 0, stream>>>(Wo, WoT, 512, 512);
  transT<<<dim3(8, 8), 256, 0, stream>>>(Wsq, WsqkvT, 512, 512);
  transT<<<dim3(8, 8), 256, 0, stream>>>(Wsk, WsqkvT + 262144, 512, 512);
  transT<<<dim3(8, 8), 256, 0, stream>>>(Wsv, WsqkvT + 524288, 512, 512);
  transT<<<dim3(8, 8), 256, 0, stream>>>(Wso, WsoT, 512, 512);
  transT<<<dim3(8, 3), 256, 0, stream>>>(Wsp, WspT, 192, 512);
  stack_bias<<<6, 256, 0, stream>>>(bq, bk, bv, bsq, bsk, bsv, bqkv, bsqkv);

  // spatial path: QKV on bt512 (proven 131.5us), O-proj back on proven R9 gemm_bt
  gemm_bt512<<<dim3(12, 392), 512, 0, stream>>>(tokbf, 512, WqkvT, 512, bqkv, qkv, 1536, 50176, 1536, 512, 1);
  win_attn_mfma<<<1024, 256, 0, stream>>>(qkv, tokbf);
  gemm_bt<<<dim3(8, 392), 256, 0, stream>>>(tokbf, 512, 0, WoT, 512, 0, bo, qkv, 512, 0, 50176, 512, 512, 1);

  // spectral path (proven R9 gemm_bt)
  dct_f2<<<3136, 192, 0, stream>>>(patches, F2b);
  gemm_bt<<<dim3(8, 25), 256, 0, stream>>>(F2b, 192, 0, WspT, 192, 0, bsp, sd, 512, 0, 3136, 512, 192, 1);
  gemm_bt<<<dim3(24, 25), 256, 0, stream>>>(sd, 512, 0, WsqkvT, 512, 0, bsqkv, qkvs, 1536, 0, 3136, 1536, 512, 1);
  gemm_bt<<<dim3(13, 7, 4), 256, 0, stream>>>(qkvs, 1536, (long)784 * 1536, qkvs + 512, 1536, (long)784 * 1536,
                                              nullptr, Sbuf, 784, (long)784 * 784, 784, 784, 512, 0);
  spec_softmax<<<3136, 256, 0, stream>>>(Sbuf, Pbuf);
  transV<<<6656, 256, 0, stream>>>(qkvs, Vt);
  gemm_bt<<<dim3(8, 7, 4), 256, 0, stream>>>(Pbuf, 832, (long)784 * 832, Vt, 832, (long)512 * 832,
                                             nullptr, sopre, 512, (long)784 * 512, 784, 512, 832, 1);
  gemm_bt<<<dim3(8, 25), 256, 0, stream>>>(sopre, 512, 0, WsoT, 512, 0, bso, sofin, 512, 0, 3136, 512, 512, 0);

  // combine + LN
  combine_ln<<<50176, 256, 0, stream>>>(tokens, qkv, sofin, alpha, out);
}

// Round 14
// 459.358 us; speedup vs baseline: 1.6954x; 1.1178x over previous
//
#include <hip/hip_runtime.h>

typedef unsigned short u16;
typedef __attribute__((ext_vector_type(4))) float f32x4;
typedef __attribute__((ext_vector_type(8))) short bf16x8;

#define AS1 __attribute__((address_space(1)))
#define AS3 __attribute__((address_space(3)))
#define GLL(gp, lp) __builtin_amdgcn_global_load_lds((const AS1 void*)(gp), (AS3 void*)(lp), 16, 0, 0)

__device__ __forceinline__ float b2f(u16 v) { return __uint_as_float(((unsigned)v) << 16); }
__device__ __forceinline__ u16 f2b(float f) {
  unsigned u = __float_as_uint(f);
  u += 0x7fffu + ((u >> 16) & 1u);
  return (u16)(u >> 16);
}
__device__ __forceinline__ unsigned pack2(float a, float b) {
  return (unsigned)f2b(a) | ((unsigned)f2b(b) << 16);
}
__device__ __forceinline__ float blo(unsigned u) { return __uint_as_float(u << 16); }
__device__ __forceinline__ float bhi(unsigned u) { return __uint_as_float(u & 0xffff0000u); }

// ---------------- 512-thread 128x128-tile GEMM: QKV only (proven R12/R13, ~130us) ----------------
__global__ __launch_bounds__(512, 6) void gemm_bt512(
    const u16* __restrict__ A, int lda,
    const u16* __restrict__ Bt, int ldb,
    const float* __restrict__ bias, void* __restrict__ Cv, int ldc,
    int M, int N, int K, int c_bf16)
{
  __shared__ __align__(16) u16 ldsA[128 * 64];
  __shared__ __align__(16) u16 ldsB[128 * 64];
  int tid = threadIdx.x;
  int wid = tid >> 6, lane = tid & 63;
  int lm = lane & 15, lg = lane >> 4;
  int wm = wid >> 2, wn = wid & 3;

  int nbx = gridDim.x;
  int lin = blockIdx.y * nbx + blockIdx.x;
  int nwg = nbx * gridDim.y;
  int qc = nwg >> 3, rc = nwg & 7;
  int xcd = lin & 7, pos = lin >> 3;
  int nlin = (xcd < rc ? xcd * (qc + 1) : rc * (qc + 1) + (xcd - rc) * qc) + pos;
  int bx = nlin % nbx, by = nlin / nbx;

  int row0 = by << 7;
  int col0 = bx << 7;
  int wr = wm << 6, wc = wn << 5;

  const u16* pA[2];
  const u16* pB[2];
  int ldso[2];
#pragma unroll
  for (int q = 0; q < 2; ++q) {
    int o = (q << 13) + (tid << 4);
    int r = o >> 7;
    int cs = (o >> 4) & 7;
    int cl = cs ^ (r & 7);
    int ar = row0 + r; ar = ar < M ? ar : M - 1;
    int br = col0 + r; br = br < N ? br : N - 1;
    pA[q] = A + (size_t)ar * lda + (cl << 3);
    pB[q] = Bt + (size_t)br * ldb + (cl << 3);
    ldso[q] = o >> 1;
  }

  f32x4 acc[4][2];
#pragma unroll
  for (int i = 0; i < 4; ++i)
#pragma unroll
    for (int j = 0; j < 2; ++j) { f32x4 z = {0.f, 0.f, 0.f, 0.f}; acc[i][j] = z; }

  int nt = K >> 6;
  for (int t = 0; t < nt; ++t) {
#pragma unroll
    for (int q = 0; q < 2; ++q) {
      GLL(pA[q], ldsA + ldso[q]);
      GLL(pB[q], ldsB + ldso[q]);
      pA[q] += 64; pB[q] += 64;
    }
    __syncthreads();
#pragma unroll
    for (int kk = 0; kk < 2; ++kk) {
      bf16x8 af[4], bg[2];
#pragma unroll
      for (int mi = 0; mi < 4; ++mi) {
        int r = wr + (mi << 4) + lm;
        int cs = ((kk << 2) + lg) ^ (r & 7);
        af[mi] = *(const bf16x8*)(ldsA + (r << 6) + (cs << 3));
      }
#pragma unroll
      for (int ni = 0; ni < 2; ++ni) {
        int r = wc + (ni << 4) + lm;
        int cs = ((kk << 2) + lg) ^ (r & 7);
        bg[ni] = *(const bf16x8*)(ldsB + (r << 6) + (cs << 3));
      }
#pragma unroll
      for (int mi = 0; mi < 4; ++mi)
#pragma unroll
        for (int ni = 0; ni < 2; ++ni)
          acc[mi][ni] = __builtin_amdgcn_mfma_f32_16x16x32_bf16(af[mi], bg[ni], acc[mi][ni], 0, 0, 0);
    }
    __syncthreads();
  }

#pragma unroll
  for (int mi = 0; mi < 4; ++mi) {
    int rb = row0 + wr + (mi << 4) + (lg << 2);
#pragma unroll
    for (int ni = 0; ni < 2; ++ni) {
      int c = col0 + wc + (ni << 4) + lm;
      float bv = (bias && c < N) ? bias[c] : 0.f;
#pragma unroll
      for (int j = 0; j < 4; ++j) {
        int r = rb + j;
        if (r < M && c < N) {
          float v = acc[mi][ni][j] + bv;
          if (c_bf16) ((u16*)Cv)[(size_t)r * ldc + c] = f2b(v);
          else ((float*)Cv)[(size_t)r * ldc + c] = v;
        }
      }
    }
  }
}

// ---------------- 128x64-tile GEMM (R9, proven): O-proj + batched / odd shapes ----------------
__global__ __launch_bounds__(256, 6) void gemm_bt(
    const u16* __restrict__ A, int lda, long sAb,
    const u16* __restrict__ Bt, int ldb, long sBb,
    const float* __restrict__ bias, void* __restrict__ Cv, int ldc, long sCb,
    int M, int N, int K, int c_bf16)
{
  __shared__ __align__(16) u16 ldsA[128 * 64];
  __shared__ __align__(16) u16 ldsB[64 * 64];
  int tid = threadIdx.x;
  int wid = tid >> 6, lane = tid & 63;

  int nbx = gridDim.x;
  int lin = blockIdx.y * nbx + blockIdx.x;
  int nwg = nbx * gridDim.y;
  int qc = nwg >> 3, rc = nwg & 7;
  int xcd = lin & 7, pos = lin >> 3;
  int nlin = (xcd < rc ? xcd * (qc + 1) : rc * (qc + 1) + (xcd - rc) * qc) + pos;
  int bx = nlin % nbx, by = nlin / nbx;

  int row0 = by << 7;
  int col0 = bx << 6;
  int bz = blockIdx.z;
  A += (size_t)bz * sAb;
  Bt += (size_t)bz * sBb;
  int wr = (wid >> 1) << 6, wc = (wid & 1) << 5;

  const u16* pA[4];
  const u16* pB[2];
  int ldsoA[4], ldsoB[2];
#pragma unroll
  for (int q = 0; q < 4; ++q) {
    int inst = (wid << 2) + q;
    int o = (inst << 10) + (lane << 4);
    int r = o >> 7;
    int cs = (o >> 4) & 7;
    int cl = cs ^ (r & 7);
    int ar = row0 + r; ar = ar < M ? ar : M - 1;
    pA[q] = A + (size_t)ar * lda + (cl << 3);
    ldsoA[q] = inst << 9;
  }
#pragma unroll
  for (int q = 0; q < 2; ++q) {
    int inst = (wid << 1) + q;
    int o = (inst << 10) + (lane << 4);
    int r = o >> 7;
    int cs = (o >> 4) & 7;
    int cl = cs ^ (r & 7);
    int br = col0 + r; br = br < N ? br : N - 1;
    pB[q] = Bt + (size_t)br * ldb + (cl << 3);
    ldsoB[q] = inst << 9;
  }

  f32x4 acc[4][2];
#pragma unroll
  for (int i = 0; i < 4; ++i)
#pragma unroll
    for (int j = 0; j < 2; ++j) { f32x4 z = {0.f, 0.f, 0.f, 0.f}; acc[i][j] = z; }

  int nt = K >> 6;
  for (int t = 0; t < nt; ++t) {
#pragma unroll
    for (int q = 0; q < 4; ++q) { GLL(pA[q], ldsA + ldsoA[q]); pA[q] += 64; }
#pragma unroll
    for (int q = 0; q < 2; ++q) { GLL(pB[q], ldsB + ldsoB[q]); pB[q] += 64; }
    __syncthreads();
#pragma unroll
    for (int kk = 0; kk < 2; ++kk) {
      bf16x8 af[4], bg[2];
#pragma unroll
      for (int mi = 0; mi < 4; ++mi) {
        int r = wr + (mi << 4) + (lane & 15);
        int cs = ((kk << 2) + (lane >> 4)) ^ (r & 7);
        af[mi] = *(const bf16x8*)(ldsA + (r << 6) + (cs << 3));
      }
#pragma unroll
      for (int ni = 0; ni < 2; ++ni) {
        int r = wc + (ni << 4) + (lane & 15);
        int cs = ((kk << 2) + (lane >> 4)) ^ (r & 7);
        bg[ni] = *(const bf16x8*)(ldsB + (r << 6) + (cs << 3));
      }
#pragma unroll
      for (int mi = 0; mi < 4; ++mi)
#pragma unroll
        for (int ni = 0; ni < 2; ++ni)
          acc[mi][ni] = __builtin_amdgcn_mfma_f32_16x16x32_bf16(af[mi], bg[ni], acc[mi][ni], 0, 0, 0);
    }
    __syncthreads();
  }

#pragma unroll
  for (int mi = 0; mi < 4; ++mi) {
    int rb = row0 + wr + (mi << 4) + ((lane >> 4) << 2);
#pragma unroll
    for (int ni = 0; ni < 2; ++ni) {
      int c = col0 + wc + (ni << 4) + (lane & 15);
      float bv = (bias && c < N) ? bias[c] : 0.f;
#pragma unroll
      for (int j = 0; j < 4; ++j) {
        int r = rb + j;
        if (r < M && c < N) {
          float v = acc[mi][ni][j] + bv;
          if (c_bf16) ((u16*)Cv)[(size_t)bz * sCb + (size_t)r * ldc + c] = f2b(v);
          else ((float*)Cv)[(size_t)bz * sCb + (size_t)r * ldc + c] = v;
        }
      }
    }
  }
}

// ---------------- window attention via MFMA: 1 block per window, wave = head group ----------------
__global__ __launch_bounds__(256, 2) void win_attn_mfma(const u16* __restrict__ qkv, u16* __restrict__ oat)
{
  __shared__ __align__(16) u16 Pl[4][64 * 72];
  __shared__ __align__(16) u16 Vtl[4][32 * 72];
  int tid = threadIdx.x;
  int wid = tid >> 6, lane = tid & 63;
  int lm = lane & 15, lg = lane >> 4;
  int w = blockIdx.x;
  int b = w >> 8, wh = (w >> 4) & 15, ww = w & 15;
  int rowbase = (wh * 7) * 112 + ww * 7;
  u16* P = Pl[wid];
  u16* Vt = Vtl[wid];
  const u16* base = qkv + (size_t)b * 12544 * 1536;
  u16* ob = oat + (size_t)b * 12544 * 512;
  const float scale = 0.17677669529663687f;

  for (int hh = 0; hh < 4; ++hh) {
    int h = wid * 4 + hh;
    bf16x8 Qf[4], Kf[4];
#pragma unroll
    for (int mi = 0; mi < 4; ++mi) {
      int i = mi * 16 + lm; i = i < 49 ? i : 48;
      int q7 = (i * 147) >> 10;
      int n = rowbase + q7 * 112 + (i - q7 * 7);
      const u16* rp = base + (size_t)n * 1536 + h * 32 + lg * 8;
      Qf[mi] = *(const bf16x8*)(rp);
      Kf[mi] = *(const bf16x8*)(rp + 512);
    }
    {
      int j = lane;
      if (j < 49) {
        int q7 = (j * 147) >> 10;
        int n = rowbase + q7 * 112 + (j - q7 * 7);
        const uint4* vp = (const uint4*)(base + (size_t)n * 1536 + 1024 + h * 32);
#pragma unroll
        for (int t = 0; t < 4; ++t) {
          uint4 u = vp[t];
          Vt[(t * 8 + 0) * 72 + j] = (u16)(u.x & 0xffff); Vt[(t * 8 + 1) * 72 + j] = (u16)(u.x >> 16);
          Vt[(t * 8 + 2) * 72 + j] = (u16)(u.y & 0xffff); Vt[(t * 8 + 3) * 72 + j] = (u16)(u.y >> 16);
          Vt[(t * 8 + 4) * 72 + j] = (u16)(u.z & 0xffff); Vt[(t * 8 + 5) * 72 + j] = (u16)(u.z >> 16);
          Vt[(t * 8 + 6) * 72 + j] = (u16)(u.w & 0xffff); Vt[(t * 8 + 7) * 72 + j] = (u16)(u.w >> 16);
        }
      } else {
#pragma unroll
        for (int d = 0; d < 32; ++d) Vt[d * 72 + j] = 0;
      }
    }
    f32x4 S[4][4];
#pragma unroll
    for (int mi = 0; mi < 4; ++mi)
#pragma unroll
      for (int nj = 0; nj < 4; ++nj) { f32x4 z = {0.f, 0.f, 0.f, 0.f}; S[mi][nj] = z; }
#pragma unroll
    for (int mi = 0; mi < 4; ++mi)
#pragma unroll
      for (int nj = 0; nj < 4; ++nj)
        S[mi][nj] = __builtin_amdgcn_mfma_f32_16x16x32_bf16(Qf[mi], Kf[nj], S[mi][nj], 0, 0, 0);
    float invv[4][4];
#pragma unroll
    for (int mi = 0; mi < 4; ++mi) {
#pragma unroll
      for (int reg = 0; reg < 4; ++reg) {
        float v0 = S[mi][0][reg], v1 = S[mi][1][reg], v2 = S[mi][2][reg], v3 = S[mi][3][reg];
        if (lm) v3 = -1e30f;
        float m = fmaxf(fmaxf(v0, v1), fmaxf(v2, v3));
#pragma unroll
        for (int o = 1; o < 16; o <<= 1) m = fmaxf(m, __shfl_xor(m, o));
        float e0 = __expf((v0 - m) * scale);
        float e1 = __expf((v1 - m) * scale);
        float e2 = __expf((v2 - m) * scale);
        float e3 = lm ? 0.f : __expf((v3 - m) * scale);
        float s = e0 + e1 + e2 + e3;
#pragma unroll
        for (int o = 1; o < 16; o <<= 1) s += __shfl_xor(s, o);
        invv[mi][reg] = 1.f / s;
        int r = mi * 16 + lg * 4 + reg;
        P[r * 72 + lm] = f2b(e0);
        P[r * 72 + 16 + lm] = f2b(e1);
        P[r * 72 + 32 + lm] = f2b(e2);
        P[r * 72 + 48 + lm] = f2b(e3);
      }
    }
    bf16x8 Vf[2][2];
#pragma unroll
    for (int dt = 0; dt < 2; ++dt) {
      Vf[dt][0] = *(const bf16x8*)(Vt + (dt * 16 + lm) * 72 + lg * 8);
      Vf[dt][1] = *(const bf16x8*)(Vt + (dt * 16 + lm) * 72 + 32 + lg * 8);
    }
    f32x4 O[4][2];
#pragma unroll
    for (int mi = 0; mi < 4; ++mi)
#pragma unroll
      for (int dt = 0; dt < 2; ++dt) { f32x4 z = {0.f, 0.f, 0.f, 0.f}; O[mi][dt] = z; }
#pragma unroll
    for (int mi = 0; mi < 4; ++mi) {
      bf16x8 Pf0 = *(const bf16x8*)(P + (mi * 16 + lm) * 72 + lg * 8);
      bf16x8 Pf1 = *(const bf16x8*)(P + (mi * 16 + lm) * 72 + 32 + lg * 8);
#pragma unroll
      for (int dt = 0; dt < 2; ++dt) {
        O[mi][dt] = __builtin_amdgcn_mfma_f32_16x16x32_bf16(Pf0, Vf[dt][0], O[mi][dt], 0, 0, 0);
        O[mi][dt] = __builtin_amdgcn_mfma_f32_16x16x32_bf16(Pf1, Vf[dt][1], O[mi][dt], 0, 0, 0);
      }
    }
#pragma unroll
    for (int mi = 0; mi < 4; ++mi)
#pragma unroll
      for (int reg = 0; reg < 4; ++reg) {
        int i = mi * 16 + lg * 4 + reg;
        if (i < 49) {
          int q7 = (i * 147) >> 10;
          int n = rowbase + q7 * 112 + (i - q7 * 7);
          float iv = invv[mi][reg];
          u16* op = ob + (size_t)n * 512 + h * 32 + lm;
          op[0] = f2b(O[mi][0][reg] * iv);
          op[16] = f2b(O[mi][1][reg] * iv);
        }
      }
  }
}

// ---------------- DCT of 8x8 patches at subsampled positions -> F2 (3136 x 192) bf16 ----------------
__global__ __launch_bounds__(192) void dct_f2(const float* __restrict__ patches, u16* __restrict__ F2)
{
  __shared__ float pv[192];
  __shared__ float Bm[64];
  int blk = blockIdx.x;
  int b = blk / 784, rem = blk % 784;
  int n = ((rem / 28) * 4) * 112 + (rem % 28) * 4;
  int t = threadIdx.x;
  if (t < 64) {
    int k = t >> 3, ii = t & 7;
    float v = cosf(3.14159265358979323846f * (ii + 0.5f) * (float)k * 0.125f) * 0.5f;
    if (k == 0) v *= 0.70710678118654752f;
    Bm[t] = v;
  }
  pv[t] = patches[((size_t)b * 192 + t) * 12544 + n];
  __syncthreads();
  int c = t >> 6, fi = (t >> 3) & 7, fk = t & 7;
  float acc = 0.f;
#pragma unroll
  for (int mm = 0; mm < 8; ++mm) {
    float g = 0.f;
#pragma unroll
    for (int jj = 0; jj < 8; ++jj) g += pv[c * 64 + mm * 8 + jj] * Bm[jj * 8 + fk];
    acc += Bm[fi * 8 + mm] * g;
  }
  F2[(size_t)blk * 192 + t] = f2b(acc);
}

// ---------------- spectral softmax: 1 block per row, 784 cols -> bf16 P (padded to 832) ----------------
__global__ __launch_bounds__(256) void spec_softmax(const float* __restrict__ S, u16* __restrict__ P)
{
  __shared__ float red[4];
  int row = blockIdx.x;
  const float* sr = S + (size_t)row * 784;
  u16* pr = P + (size_t)row * 832;
  int t = threadIdx.x;
  int lane = t & 63, wid = t >> 6;
  float v0 = sr[t];
  float v1 = sr[t + 256];
  float v2 = (t < 272) ? sr[t + 512] : -1e30f;
  float m = fmaxf(fmaxf(v0, v1), v2);
#pragma unroll
  for (int ofs = 32; ofs > 0; ofs >>= 1) m = fmaxf(m, __shfl_xor(m, ofs));
  if (lane == 0) red[wid] = m;
  __syncthreads();
  m = fmaxf(fmaxf(red[0], red[1]), fmaxf(red[2], red[3]));
  __syncthreads();
  const float scale = 0.044194173824159216f;
  float e0 = __expf((v0 - m) * scale);
  float e1 = __expf((v1 - m) * scale);
  float e2 = (t < 272) ? __expf((v2 - m) * scale) : 0.f;
  float sum = e0 + e1 + e2;
#pragma unroll
  for (int ofs = 32; ofs > 0; ofs >>= 1) sum += __shfl_xor(sum, ofs);
  if (lane == 0) red[wid] = sum;
  __syncthreads();
  sum = red[0] + red[1] + red[2] + red[3];
  float inv = 1.f / sum;
  pr[t] = f2b(e0 * inv);
  pr[t + 256] = f2b(e1 * inv);
  if (t < 272) pr[t + 512] = f2b(e2 * inv);
  else if (t < 320) pr[t + 512] = 0;
}

// ---------------- V transpose for PV gemm: Vt[b][n][k] = V[b][k][n], k padded to 832 ----------------
__global__ __launch_bounds__(256) void transV(const u16* __restrict__ qkvs, u16* __restrict__ Vt)
{
  int idx = blockIdx.x * 256 + threadIdx.x;
  int k = idx % 832;
  int rest = idx / 832;
  int n = rest % 512, b = rest / 512;
  u16 v = 0;
  if (k < 784) v = qkvs[((size_t)(b * 784 + k)) * 1536 + 1024 + n];
  Vt[idx] = v;
}

// ---------------- combine + nearest-upsample gather + LayerNorm ----------------
__global__ __launch_bounds__(256) void combine_ln(
    const float* __restrict__ tokens, const u16* __restrict__ sp,
    const float* __restrict__ so, const float* __restrict__ alpha,
    float* __restrict__ out)
{
  int nidx = blockIdx.x;
  int b = nidx / 12544, pos = nidx % 12544;
  int i = pos / 112, j = pos % 112;
  const float* tr = tokens + (size_t)nidx * 512;
  const u16* sr = sp + (size_t)nidx * 512;
  const float* qr = so + (size_t)(b * 784 + (i >> 2) * 28 + (j >> 2)) * 512;
  float al = 1.f / (1.f + __expf(-alpha[0]));
  float be = 1.f - al;
  int t = threadIdx.x;
  float x0 = tr[t] + al * b2f(sr[t]) + be * qr[t];
  float x1 = tr[t + 256] + al * b2f(sr[t + 256]) + be * qr[t + 256];
  float s = x0 + x1, ss = x0 * x0 + x1 * x1;
#pragma unroll
  for (int ofs = 32; ofs > 0; ofs >>= 1) { s += __shfl_xor(s, ofs); ss += __shfl_xor(ss, ofs); }
  __shared__ float rs[4], rq[4];
  int lane = t & 63, wid = t >> 6;
  if (lane == 0) { rs[wid] = s; rq[wid] = ss; }
  __syncthreads();
  s = rs[0] + rs[1] + rs[2] + rs[3];
  ss = rq[0] + rq[1] + rq[2] + rq[3];
  float mu = s * 0.001953125f;
  float var = ss * 0.001953125f - mu * mu;
  float rstd = rsqrtf(var + 1e-5f);
  float* orow = out + (size_t)nidx * 512;
  orow[t] = (x0 - mu) * rstd;
  orow[t + 256] = (x1 - mu) * rstd;
}

// ---------------- small prep kernels (R9 originals: high-parallelism strided transpose) ----------------
__global__ __launch_bounds__(256) void transT(const float* __restrict__ src, u16* __restrict__ dst, int K, int Nc)
{
  int idx = blockIdx.x * 256 + threadIdx.x;
  if (idx >= K * Nc) return;
  int nn = idx / K, kk = idx % K;
  dst[idx] = f2b(src[(size_t)kk * Nc + nn]);
}

__global__ __launch_bounds__(256) void cvtbf(const float* __restrict__ src, u16* __restrict__ dst)
{
  size_t i = ((size_t)blockIdx.x * 256 + threadIdx.x) * 4;
  float4 v = *(const float4*)(src + i);
  uint2 u;
  u.x = pack2(v.x, v.y);
  u.y = pack2(v.z, v.w);
  *(uint2*)(dst + i) = u;
}

__global__ __launch_bounds__(256) void stack_bias(
    const float* bq_, const float* bk_, const float* bv_,
    const float* bsq_, const float* bsk_, const float* bsv_,
    float* bqkv, float* bsqkv)
{
  int i = blockIdx.x * 256 + threadIdx.x;
  if (i >= 1536) return;
  int r = i & 511;
  bqkv[i]  = (i < 512) ? bq_[r]  : (i < 1024) ? bk_[r]  : bv_[r];
  bsqkv[i] = (i < 512) ? bsq_[r] : (i < 1024) ? bsk_[r] : bsv_[r];
}

// ---------------- launch ----------------
extern "C" void kernel_launch(void* const* d_in, const int* in_sizes, int n_in,
                              void* d_out, int out_size, void* d_ws, size_t ws_size,
                              hipStream_t stream) {
  (void)in_sizes; (void)n_in; (void)out_size; (void)ws_size;
  const float* tokens = (const float*)d_in[0];
  const float* patches = (const float*)d_in[1];
  const float* Wq  = (const float*)d_in[2];
  const float* bq  = (const float*)d_in[3];
  const float* Wk  = (const float*)d_in[4];
  const float* bk  = (const float*)d_in[5];
  const float* Wv  = (const float*)d_in[6];
  const float* bv  = (const float*)d_in[7];
  const float* Wo  = (const float*)d_in[8];
  const float* bo  = (const float*)d_in[9];
  const float* Wsp = (const float*)d_in[10];
  const float* bsp = (const float*)d_in[11];
  const float* Wsq = (const float*)d_in[12];
  const float* bsq = (const float*)d_in[13];
  const float* Wsk = (const float*)d_in[14];
  const float* bsk = (const float*)d_in[15];
  const float* Wsv = (const float*)d_in[16];
  const float* bsv = (const float*)d_in[17];
  const float* Wso = (const float*)d_in[18];
  const float* bso = (const float*)d_in[19];
  const float* alpha = (const float*)d_in[20];
  float* out = (float*)d_out;

  char* ws = (char*)d_ws;
  u16* tokbf  = (u16*)ws;
  u16* qkv    = (u16*)(ws + 51380224);
  char* pp    = ws + 51380224 + 154140672;
  u16* WqkvT  = (u16*)pp; pp += 1572864;
  u16* WoT    = (u16*)pp; pp += 524288;
  u16* WsqkvT = (u16*)pp; pp += 1572864;
  u16* WsoT   = (u16*)pp; pp += 524288;
  u16* WspT   = (u16*)pp; pp += 196608;
  float* bqkv = (float*)pp; pp += 6144;
  float* bsqkv= (float*)pp; pp += 6144;
  u16* F2b    = (u16*)pp; pp += 1204224;
  u16* sd     = (u16*)pp; pp += 3211264;
  u16* qkvs   = (u16*)pp; pp += 9633792;
  u16* sopre  = (u16*)pp; pp += 3211264;
  float* sofin= (float*)pp; pp += 6422528;

  float* Sbuf = (float*)tokbf;
  u16* Pbuf   = (u16*)(ws + 9834496);
  u16* Vt     = (u16*)(ws + 9834496 + 5218304);

  // prep (R9 originals)
  cvtbf<<<25088, 256, 0, stream>>>(tokens, tokbf);
  transT<<<1024, 256, 0, stream>>>(Wq, WqkvT, 512, 512);
  transT<<<1024, 256, 0, stream>>>(Wk, WqkvT + 262144, 512, 512);
  transT<<<1024, 256, 0, stream>>>(Wv, WqkvT + 524288, 512, 512);
  transT<<<1024, 256, 0, stream>>>(Wo, WoT, 512, 512);
  transT<<<1024, 256, 0, stream>>>(Wsq, WsqkvT, 512, 512);
  transT<<<1024, 256, 0, stream>>>(Wsk, WsqkvT + 262144, 512, 512);
  transT<<<1024, 256, 0, stream>>>(Wsv, WsqkvT + 524288, 512, 512);
  transT<<<1024, 256, 0, stream>>>(Wso, WsoT, 512, 512);
  transT<<<384, 256, 0, stream>>>(Wsp, WspT, 192, 512);
  stack_bias<<<6, 256, 0, stream>>>(bq, bk, bv, bsq, bsk, bsv, bqkv, bsqkv);

  // spatial path: QKV on bt512 (proven ~130us); O-proj on proven R9 gemm_bt
  gemm_bt512<<<dim3(12, 392), 512, 0, stream>>>(tokbf, 512, WqkvT, 512, bqkv, qkv, 1536, 50176, 1536, 512, 1);
  win_attn_mfma<<<1024, 256, 0, stream>>>(qkv, tokbf);
  gemm_bt<<<dim3(8, 392), 256, 0, stream>>>(tokbf, 512, 0, WoT, 512, 0, bo, qkv, 512, 0, 50176, 512, 512, 1);

  // spectral path (proven R9 gemm_bt)
  dct_f2<<<3136, 192, 0, stream>>>(patches, F2b);
  gemm_bt<<<dim3(8, 25), 256, 0, stream>>>(F2b, 192, 0, WspT, 192, 0, bsp, sd, 512, 0, 3136, 512, 192, 1);
  gemm_bt<<<dim3(24, 25), 256, 0, stream>>>(sd, 512, 0, WsqkvT, 512, 0, bsqkv, qkvs, 1536, 0, 3136, 1536, 512, 1);
  gemm_bt<<<dim3(13, 7, 4), 256, 0, stream>>>(qkvs, 1536, (long)784 * 1536, qkvs + 512, 1536, (long)784 * 1536,
                                              nullptr, Sbuf, 784, (long)784 * 784, 784, 784, 512, 0);
  spec_softmax<<<3136, 256, 0, stream>>>(Sbuf, Pbuf);
  transV<<<6656, 256, 0, stream>>>(qkvs, Vt);
  gemm_bt<<<dim3(8, 7, 4), 256, 0, stream>>>(Pbuf, 832, (long)784 * 832, Vt, 832, (long)512 * 832,
                                             nullptr, sopre, 512, (long)784 * 512, 784, 512, 832, 1);
  gemm_bt<<<dim3(8, 25), 256, 0, stream>>>(sopre, 512, 0, WsoT, 512, 0, bso, sofin, 512, 0, 3136, 512, 512, 0);

  // combine + LN
  combine_ln<<<50176, 256, 0, stream>>>(tokens, qkv, sofin, alpha, out);
}

// Round 15
// 434.483 us; speedup vs baseline: 1.7925x; 1.0573x over previous
//
#include <hip/hip_runtime.h>

typedef unsigned short u16;
typedef __attribute__((ext_vector_type(4))) float f32x4;
typedef __attribute__((ext_vector_type(8))) short bf16x8;

#define AS1 __attribute__((address_space(1)))
#define AS3 __attribute__((address_space(3)))
#define GLL(gp, lp) __builtin_amdgcn_global_load_lds((const AS1 void*)(gp), (AS3 void*)(lp), 16, 0, 0)

__device__ __forceinline__ float b2f(u16 v) { return __uint_as_float(((unsigned)v) << 16); }
__device__ __forceinline__ u16 f2b(float f) {
  unsigned u = __float_as_uint(f);
  u += 0x7fffu + ((u >> 16) & 1u);
  return (u16)(u >> 16);
}
__device__ __forceinline__ unsigned pack2(float a, float b) {
  return (unsigned)f2b(a) | ((unsigned)f2b(b) << 16);
}
__device__ __forceinline__ float blo(unsigned u) { return __uint_as_float(u << 16); }
__device__ __forceinline__ float bhi(unsigned u) { return __uint_as_float(u & 0xffff0000u); }

// ---------------- 512-thread 128x128-tile GEMM: QKV (proven ~130us) ----------------
__global__ __launch_bounds__(512, 6) void gemm_bt512(
    const u16* __restrict__ A, int lda,
    const u16* __restrict__ Bt, int ldb,
    const float* __restrict__ bias, void* __restrict__ Cv, int ldc,
    int M, int N, int K, int c_bf16)
{
  __shared__ __align__(16) u16 ldsA[128 * 64];
  __shared__ __align__(16) u16 ldsB[128 * 64];
  int tid = threadIdx.x;
  int wid = tid >> 6, lane = tid & 63;
  int lm = lane & 15, lg = lane >> 4;
  int wm = wid >> 2, wn = wid & 3;

  int nbx = gridDim.x;
  int lin = blockIdx.y * nbx + blockIdx.x;
  int nwg = nbx * gridDim.y;
  int qc = nwg >> 3, rc = nwg & 7;
  int xcd = lin & 7, pos = lin >> 3;
  int nlin = (xcd < rc ? xcd * (qc + 1) : rc * (qc + 1) + (xcd - rc) * qc) + pos;
  int bx = nlin % nbx, by = nlin / nbx;

  int row0 = by << 7;
  int col0 = bx << 7;
  int wr = wm << 6, wc = wn << 5;

  const u16* pA[2];
  const u16* pB[2];
  int ldso[2];
#pragma unroll
  for (int q = 0; q < 2; ++q) {
    int o = (q << 13) + (tid << 4);
    int r = o >> 7;
    int cs = (o >> 4) & 7;
    int cl = cs ^ (r & 7);
    int ar = row0 + r; ar = ar < M ? ar : M - 1;
    int br = col0 + r; br = br < N ? br : N - 1;
    pA[q] = A + (size_t)ar * lda + (cl << 3);
    pB[q] = Bt + (size_t)br * ldb + (cl << 3);
    ldso[q] = o >> 1;
  }

  f32x4 acc[4][2];
#pragma unroll
  for (int i = 0; i < 4; ++i)
#pragma unroll
    for (int j = 0; j < 2; ++j) { f32x4 z = {0.f, 0.f, 0.f, 0.f}; acc[i][j] = z; }

  int nt = K >> 6;
  for (int t = 0; t < nt; ++t) {
#pragma unroll
    for (int q = 0; q < 2; ++q) {
      GLL(pA[q], ldsA + ldso[q]);
      GLL(pB[q], ldsB + ldso[q]);
      pA[q] += 64; pB[q] += 64;
    }
    __syncthreads();
#pragma unroll
    for (int kk = 0; kk < 2; ++kk) {
      bf16x8 af[4], bg[2];
#pragma unroll
      for (int mi = 0; mi < 4; ++mi) {
        int r = wr + (mi << 4) + lm;
        int cs = ((kk << 2) + lg) ^ (r & 7);
        af[mi] = *(const bf16x8*)(ldsA + (r << 6) + (cs << 3));
      }
#pragma unroll
      for (int ni = 0; ni < 2; ++ni) {
        int r = wc + (ni << 4) + lm;
        int cs = ((kk << 2) + lg) ^ (r & 7);
        bg[ni] = *(const bf16x8*)(ldsB + (r << 6) + (cs << 3));
      }
#pragma unroll
      for (int mi = 0; mi < 4; ++mi)
#pragma unroll
        for (int ni = 0; ni < 2; ++ni)
          acc[mi][ni] = __builtin_amdgcn_mfma_f32_16x16x32_bf16(af[mi], bg[ni], acc[mi][ni], 0, 0, 0);
    }
    __syncthreads();
  }

#pragma unroll
  for (int mi = 0; mi < 4; ++mi) {
    int rb = row0 + wr + (mi << 4) + (lg << 2);
#pragma unroll
    for (int ni = 0; ni < 2; ++ni) {
      int c = col0 + wc + (ni << 4) + lm;
      float bv = (bias && c < N) ? bias[c] : 0.f;
#pragma unroll
      for (int j = 0; j < 4; ++j) {
        int r = rb + j;
        if (r < M && c < N) {
          float v = acc[mi][ni][j] + bv;
          if (c_bf16) ((u16*)Cv)[(size_t)r * ldc + c] = f2b(v);
          else ((float*)Cv)[(size_t)r * ldc + c] = v;
        }
      }
    }
  }
}

// ---------------- 128x64-tile GEMM (R9, proven): O-proj + batched / odd shapes ----------------
__global__ __launch_bounds__(256, 6) void gemm_bt(
    const u16* __restrict__ A, int lda, long sAb,
    const u16* __restrict__ Bt, int ldb, long sBb,
    const float* __restrict__ bias, void* __restrict__ Cv, int ldc, long sCb,
    int M, int N, int K, int c_bf16)
{
  __shared__ __align__(16) u16 ldsA[128 * 64];
  __shared__ __align__(16) u16 ldsB[64 * 64];
  int tid = threadIdx.x;
  int wid = tid >> 6, lane = tid & 63;

  int nbx = gridDim.x;
  int lin = blockIdx.y * nbx + blockIdx.x;
  int nwg = nbx * gridDim.y;
  int qc = nwg >> 3, rc = nwg & 7;
  int xcd = lin & 7, pos = lin >> 3;
  int nlin = (xcd < rc ? xcd * (qc + 1) : rc * (qc + 1) + (xcd - rc) * qc) + pos;
  int bx = nlin % nbx, by = nlin / nbx;

  int row0 = by << 7;
  int col0 = bx << 6;
  int bz = blockIdx.z;
  A += (size_t)bz * sAb;
  Bt += (size_t)bz * sBb;
  int wr = (wid >> 1) << 6, wc = (wid & 1) << 5;

  const u16* pA[4];
  const u16* pB[2];
  int ldsoA[4], ldsoB[2];
#pragma unroll
  for (int q = 0; q < 4; ++q) {
    int inst = (wid << 2) + q;
    int o = (inst << 10) + (lane << 4);
    int r = o >> 7;
    int cs = (o >> 4) & 7;
    int cl = cs ^ (r & 7);
    int ar = row0 + r; ar = ar < M ? ar : M - 1;
    pA[q] = A + (size_t)ar * lda + (cl << 3);
    ldsoA[q] = inst << 9;
  }
#pragma unroll
  for (int q = 0; q < 2; ++q) {
    int inst = (wid << 1) + q;
    int o = (inst << 10) + (lane << 4);
    int r = o >> 7;
    int cs = (o >> 4) & 7;
    int cl = cs ^ (r & 7);
    int br = col0 + r; br = br < N ? br : N - 1;
    pB[q] = Bt + (size_t)br * ldb + (cl << 3);
    ldsoB[q] = inst << 9;
  }

  f32x4 acc[4][2];
#pragma unroll
  for (int i = 0; i < 4; ++i)
#pragma unroll
    for (int j = 0; j < 2; ++j) { f32x4 z = {0.f, 0.f, 0.f, 0.f}; acc[i][j] = z; }

  int nt = K >> 6;
  for (int t = 0; t < nt; ++t) {
#pragma unroll
    for (int q = 0; q < 4; ++q) { GLL(pA[q], ldsA + ldsoA[q]); pA[q] += 64; }
#pragma unroll
    for (int q = 0; q < 2; ++q) { GLL(pB[q], ldsB + ldsoB[q]); pB[q] += 64; }
    __syncthreads();
#pragma unroll
    for (int kk = 0; kk < 2; ++kk) {
      bf16x8 af[4], bg[2];
#pragma unroll
      for (int mi = 0; mi < 4; ++mi) {
        int r = wr + (mi << 4) + (lane & 15);
        int cs = ((kk << 2) + (lane >> 4)) ^ (r & 7);
        af[mi] = *(const bf16x8*)(ldsA + (r << 6) + (cs << 3));
      }
#pragma unroll
      for (int ni = 0; ni < 2; ++ni) {
        int r = wc + (ni << 4) + (lane & 15);
        int cs = ((kk << 2) + (lane >> 4)) ^ (r & 7);
        bg[ni] = *(const bf16x8*)(ldsB + (r << 6) + (cs << 3));
      }
#pragma unroll
      for (int mi = 0; mi < 4; ++mi)
#pragma unroll
        for (int ni = 0; ni < 2; ++ni)
          acc[mi][ni] = __builtin_amdgcn_mfma_f32_16x16x32_bf16(af[mi], bg[ni], acc[mi][ni], 0, 0, 0);
    }
    __syncthreads();
  }

#pragma unroll
  for (int mi = 0; mi < 4; ++mi) {
    int rb = row0 + wr + (mi << 4) + ((lane >> 4) << 2);
#pragma unroll
    for (int ni = 0; ni < 2; ++ni) {
      int c = col0 + wc + (ni << 4) + (lane & 15);
      float bv = (bias && c < N) ? bias[c] : 0.f;
#pragma unroll
      for (int j = 0; j < 4; ++j) {
        int r = rb + j;
        if (r < M && c < N) {
          float v = acc[mi][ni][j] + bv;
          if (c_bf16) ((u16*)Cv)[(size_t)bz * sCb + (size_t)r * ldc + c] = f2b(v);
          else ((float*)Cv)[(size_t)bz * sCb + (size_t)r * ldc + c] = v;
        }
      }
    }
  }
}

// ---------------- window attention via MFMA: 1 block per (window, head-quad), wave = 1 head ----------------
// R15: grid 1024 -> 4096 (one head per wave, hh loop lifted into blockIdx) for 4x block-level
// latency overlap -- the kernel is latency-bound on per-wave serial softmax/LDS chains.
__global__ __launch_bounds__(256, 2) void win_attn_mfma(const u16* __restrict__ qkv, u16* __restrict__ oat)
{
  __shared__ __align__(16) u16 Pl[4][64 * 72];
  __shared__ __align__(16) u16 Vtl[4][32 * 72];
  int tid = threadIdx.x;
  int wid = tid >> 6, lane = tid & 63;
  int lm = lane & 15, lg = lane >> 4;
  int blk = blockIdx.x;
  int w = blk >> 2, hq = blk & 3;
  int h = hq * 4 + wid;
  int b = w >> 8, wh = (w >> 4) & 15, ww = w & 15;
  int rowbase = (wh * 7) * 112 + ww * 7;
  u16* P = Pl[wid];
  u16* Vt = Vtl[wid];
  const u16* base = qkv + (size_t)b * 12544 * 1536;
  u16* ob = oat + (size_t)b * 12544 * 512;
  const float scale = 0.17677669529663687f;

  bf16x8 Qf[4], Kf[4];
#pragma unroll
  for (int mi = 0; mi < 4; ++mi) {
    int i = mi * 16 + lm; i = i < 49 ? i : 48;
    int q7 = (i * 147) >> 10;
    int n = rowbase + q7 * 112 + (i - q7 * 7);
    const u16* rp = base + (size_t)n * 1536 + h * 32 + lg * 8;
    Qf[mi] = *(const bf16x8*)(rp);
    Kf[mi] = *(const bf16x8*)(rp + 512);
  }
  {
    int j = lane;
    if (j < 49) {
      int q7 = (j * 147) >> 10;
      int n = rowbase + q7 * 112 + (j - q7 * 7);
      const uint4* vp = (const uint4*)(base + (size_t)n * 1536 + 1024 + h * 32);
#pragma unroll
      for (int t = 0; t < 4; ++t) {
        uint4 u = vp[t];
        Vt[(t * 8 + 0) * 72 + j] = (u16)(u.x & 0xffff); Vt[(t * 8 + 1) * 72 + j] = (u16)(u.x >> 16);
        Vt[(t * 8 + 2) * 72 + j] = (u16)(u.y & 0xffff); Vt[(t * 8 + 3) * 72 + j] = (u16)(u.y >> 16);
        Vt[(t * 8 + 4) * 72 + j] = (u16)(u.z & 0xffff); Vt[(t * 8 + 5) * 72 + j] = (u16)(u.z >> 16);
        Vt[(t * 8 + 6) * 72 + j] = (u16)(u.w & 0xffff); Vt[(t * 8 + 7) * 72 + j] = (u16)(u.w >> 16);
      }
    } else {
#pragma unroll
      for (int d = 0; d < 32; ++d) Vt[d * 72 + j] = 0;
    }
  }
  f32x4 S[4][4];
#pragma unroll
  for (int mi = 0; mi < 4; ++mi)
#pragma unroll
    for (int nj = 0; nj < 4; ++nj) { f32x4 z = {0.f, 0.f, 0.f, 0.f}; S[mi][nj] = z; }
#pragma unroll
  for (int mi = 0; mi < 4; ++mi)
#pragma unroll
    for (int nj = 0; nj < 4; ++nj)
      S[mi][nj] = __builtin_amdgcn_mfma_f32_16x16x32_bf16(Qf[mi], Kf[nj], S[mi][nj], 0, 0, 0);
  float invv[4][4];
#pragma unroll
  for (int mi = 0; mi < 4; ++mi) {
#pragma unroll
    for (int reg = 0; reg < 4; ++reg) {
      float v0 = S[mi][0][reg], v1 = S[mi][1][reg], v2 = S[mi][2][reg], v3 = S[mi][3][reg];
      if (lm) v3 = -1e30f;
      float m = fmaxf(fmaxf(v0, v1), fmaxf(v2, v3));
#pragma unroll
      for (int o = 1; o < 16; o <<= 1) m = fmaxf(m, __shfl_xor(m, o));
      float e0 = __expf((v0 - m) * scale);
      float e1 = __expf((v1 - m) * scale);
      float e2 = __expf((v2 - m) * scale);
      float e3 = lm ? 0.f : __expf((v3 - m) * scale);
      float s = e0 + e1 + e2 + e3;
#pragma unroll
      for (int o = 1; o < 16; o <<= 1) s += __shfl_xor(s, o);
      invv[mi][reg] = 1.f / s;
      int r = mi * 16 + lg * 4 + reg;
      P[r * 72 + lm] = f2b(e0);
      P[r * 72 + 16 + lm] = f2b(e1);
      P[r * 72 + 32 + lm] = f2b(e2);
      P[r * 72 + 48 + lm] = f2b(e3);
    }
  }
  bf16x8 Vf[2][2];
#pragma unroll
  for (int dt = 0; dt < 2; ++dt) {
    Vf[dt][0] = *(const bf16x8*)(Vt + (dt * 16 + lm) * 72 + lg * 8);
    Vf[dt][1] = *(const bf16x8*)(Vt + (dt * 16 + lm) * 72 + 32 + lg * 8);
  }
  f32x4 O[4][2];
#pragma unroll
  for (int mi = 0; mi < 4; ++mi)
#pragma unroll
    for (int dt = 0; dt < 2; ++dt) { f32x4 z = {0.f, 0.f, 0.f, 0.f}; O[mi][dt] = z; }
#pragma unroll
  for (int mi = 0; mi < 4; ++mi) {
    bf16x8 Pf0 = *(const bf16x8*)(P + (mi * 16 + lm) * 72 + lg * 8);
    bf16x8 Pf1 = *(const bf16x8*)(P + (mi * 16 + lm) * 72 + 32 + lg * 8);
#pragma unroll
    for (int dt = 0; dt < 2; ++dt) {
      O[mi][dt] = __builtin_amdgcn_mfma_f32_16x16x32_bf16(Pf0, Vf[dt][0], O[mi][dt], 0, 0, 0);
      O[mi][dt] = __builtin_amdgcn_mfma_f32_16x16x32_bf16(Pf1, Vf[dt][1], O[mi][dt], 0, 0, 0);
    }
  }
#pragma unroll
  for (int mi = 0; mi < 4; ++mi)
#pragma unroll
    for (int reg = 0; reg < 4; ++reg) {
      int i = mi * 16 + lg * 4 + reg;
      if (i < 49) {
        int q7 = (i * 147) >> 10;
        int n = rowbase + q7 * 112 + (i - q7 * 7);
        float iv = invv[mi][reg];
        u16* op = ob + (size_t)n * 512 + h * 32 + lm;
        op[0] = f2b(O[mi][0][reg] * iv);
        op[16] = f2b(O[mi][1][reg] * iv);
      }
    }
}

// ---------------- DCT of 8x8 patches at subsampled positions -> F2 (3136 x 192) bf16 ----------------
__global__ __launch_bounds__(192) void dct_f2(const float* __restrict__ patches, u16* __restrict__ F2)
{
  __shared__ float pv[192];
  __shared__ float Bm[64];
  int blk = blockIdx.x;
  int b = blk / 784, rem = blk % 784;
  int n = ((rem / 28) * 4) * 112 + (rem % 28) * 4;
  int t = threadIdx.x;
  if (t < 64) {
    int k = t >> 3, ii = t & 7;
    float v = cosf(3.14159265358979323846f * (ii + 0.5f) * (float)k * 0.125f) * 0.5f;
    if (k == 0) v *= 0.70710678118654752f;
    Bm[t] = v;
  }
  pv[t] = patches[((size_t)b * 192 + t) * 12544 + n];
  __syncthreads();
  int c = t >> 6, fi = (t >> 3) & 7, fk = t & 7;
  float acc = 0.f;
#pragma unroll
  for (int mm = 0; mm < 8; ++mm) {
    float g = 0.f;
#pragma unroll
    for (int jj = 0; jj < 8; ++jj) g += pv[c * 64 + mm * 8 + jj] * Bm[jj * 8 + fk];
    acc += Bm[fi * 8 + mm] * g;
  }
  F2[(size_t)blk * 192 + t] = f2b(acc);
}

// ---------------- spectral softmax ----------------
__global__ __launch_bounds__(256) void spec_softmax(const float* __restrict__ S, u16* __restrict__ P)
{
  __shared__ float red[4];
  int row = blockIdx.x;
  const float* sr = S + (size_t)row * 784;
  u16* pr = P + (size_t)row * 832;
  int t = threadIdx.x;
  int lane = t & 63, wid = t >> 6;
  float v0 = sr[t];
  float v1 = sr[t + 256];
  float v2 = (t < 272) ? sr[t + 512] : -1e30f;
  float m = fmaxf(fmaxf(v0, v1), v2);
#pragma unroll
  for (int ofs = 32; ofs > 0; ofs >>= 1) m = fmaxf(m, __shfl_xor(m, ofs));
  if (lane == 0) red[wid] = m;
  __syncthreads();
  m = fmaxf(fmaxf(red[0], red[1]), fmaxf(red[2], red[3]));
  __syncthreads();
  const float scale = 0.044194173824159216f;
  float e0 = __expf((v0 - m) * scale);
  float e1 = __expf((v1 - m) * scale);
  float e2 = (t < 272) ? __expf((v2 - m) * scale) : 0.f;
  float sum = e0 + e1 + e2;
#pragma unroll
  for (int ofs = 32; ofs > 0; ofs >>= 1) sum += __shfl_xor(sum, ofs);
  if (lane == 0) red[wid] = sum;
  __syncthreads();
  sum = red[0] + red[1] + red[2] + red[3];
  float inv = 1.f / sum;
  pr[t] = f2b(e0 * inv);
  pr[t + 256] = f2b(e1 * inv);
  if (t < 272) pr[t + 512] = f2b(e2 * inv);
  else if (t < 320) pr[t + 512] = 0;
}

// ---------------- V transpose for PV gemm ----------------
__global__ __launch_bounds__(256) void transV(const u16* __restrict__ qkvs, u16* __restrict__ Vt)
{
  int idx = blockIdx.x * 256 + threadIdx.x;
  int k = idx % 832;
  int rest = idx / 832;
  int n = rest % 512, b = rest / 512;
  u16 v = 0;
  if (k < 784) v = qkvs[((size_t)(b * 784 + k)) * 1536 + 1024 + n];
  Vt[idx] = v;
}

// ---------------- combine + nearest-upsample gather + LayerNorm (float2 loads) ----------------
__global__ __launch_bounds__(256) void combine_ln(
    const float* __restrict__ tokens, const u16* __restrict__ sp,
    const float* __restrict__ so, const float* __restrict__ alpha,
    float* __restrict__ out)
{
  int nidx = blockIdx.x;
  int b = nidx / 12544, pos = nidx % 12544;
  int i = pos / 112, j = pos % 112;
  const float* tr = tokens + (size_t)nidx * 512;
  const u16* sr = sp + (size_t)nidx * 512;
  const float* qr = so + (size_t)(b * 784 + (i >> 2) * 28 + (j >> 2)) * 512;
  float al = 1.f / (1.f + __expf(-alpha[0]));
  float be = 1.f - al;
  int t = threadIdx.x;
  float2 tv = *(const float2*)(tr + 2 * t);
  unsigned sv = *(const unsigned*)(sr + 2 * t);
  float2 qv = *(const float2*)(qr + 2 * t);
  float x0 = tv.x + al * blo(sv) + be * qv.x;
  float x1 = tv.y + al * bhi(sv) + be * qv.y;
  float s = x0 + x1, ss = x0 * x0 + x1 * x1;
#pragma unroll
  for (int ofs = 32; ofs > 0; ofs >>= 1) { s += __shfl_xor(s, ofs); ss += __shfl_xor(ss, ofs); }
  __shared__ float rs[4], rq[4];
  int lane = t & 63, wid = t >> 6;
  if (lane == 0) { rs[wid] = s; rq[wid] = ss; }
  __syncthreads();
  s = rs[0] + rs[1] + rs[2] + rs[3];
  ss = rq[0] + rq[1] + rq[2] + rq[3];
  float mu = s * 0.001953125f;
  float var = ss * 0.001953125f - mu * mu;
  float rstd = rsqrtf(var + 1e-5f);
  float2 ov;
  ov.x = (x0 - mu) * rstd;
  ov.y = (x1 - mu) * rstd;
  *(float2*)(out + (size_t)nidx * 512 + 2 * t) = ov;
}

// ---------------- small prep kernels ----------------
// z-batched 512x512 transpose for the 8 square weights (one launch, overlapping)
__global__ __launch_bounds__(256) void transT8(
    const float* s0, const float* s1, const float* s2, const float* s3,
    const float* s4, const float* s5, const float* s6, const float* s7,
    u16* d0, u16* d1, u16* d2, u16* d3, u16* d4, u16* d5, u16* d6, u16* d7)
{
  const float* src; u16* dst;
  switch (blockIdx.z) {
    case 0: src = s0; dst = d0; break;
    case 1: src = s1; dst = d1; break;
    case 2: src = s2; dst = d2; break;
    case 3: src = s3; dst = d3; break;
    case 4: src = s4; dst = d4; break;
    case 5: src = s5; dst = d5; break;
    case 6: src = s6; dst = d6; break;
    default: src = s7; dst = d7; break;
  }
  int idx = blockIdx.x * 256 + threadIdx.x;
  int nn = idx >> 9, kk = idx & 511;
  dst[idx] = f2b(src[(kk << 9) + nn]);
}

__global__ __launch_bounds__(256) void transT(const float* __restrict__ src, u16* __restrict__ dst, int K, int Nc)
{
  int idx = blockIdx.x * 256 + threadIdx.x;
  if (idx >= K * Nc) return;
  int nn = idx / K, kk = idx % K;
  dst[idx] = f2b(src[(size_t)kk * Nc + nn]);
}

__global__ __launch_bounds__(256) void cvtbf(const float* __restrict__ src, u16* __restrict__ dst)
{
  size_t i = ((size_t)blockIdx.x * 256 + threadIdx.x) * 4;
  float4 v = *(const float4*)(src + i);
  uint2 u;
  u.x = pack2(v.x, v.y);
  u.y = pack2(v.z, v.w);
  *(uint2*)(dst + i) = u;
}

__global__ __launch_bounds__(256) void stack_bias(
    const float* bq_, const float* bk_, const float* bv_,
    const float* bsq_, const float* bsk_, const float* bsv_,
    float* bqkv, float* bsqkv)
{
  int i = blockIdx.x * 256 + threadIdx.x;
  if (i >= 1536) return;
  int r = i & 511;
  bqkv[i]  = (i < 512) ? bq_[r]  : (i < 1024) ? bk_[r]  : bv_[r];
  bsqkv[i] = (i < 512) ? bsq_[r] : (i < 1024) ? bsk_[r] : bsv_[r];
}

// ---------------- launch ----------------
extern "C" void kernel_launch(void* const* d_in, const int* in_sizes, int n_in,
                              void* d_out, int out_size, void* d_ws, size_t ws_size,
                              hipStream_t stream) {
  (void)in_sizes; (void)n_in; (void)out_size; (void)ws_size;
  const float* tokens = (const float*)d_in[0];
  const float* patches = (const float*)d_in[1];
  const float* Wq  = (const float*)d_in[2];
  const float* bq  = (const float*)d_in[3];
  const float* Wk  = (const float*)d_in[4];
  const float* bk  = (const float*)d_in[5];
  const float* Wv  = (const float*)d_in[6];
  const float* bv  = (const float*)d_in[7];
  const float* Wo  = (const float*)d_in[8];
  const float* bo  = (const float*)d_in[9];
  const float* Wsp = (const float*)d_in[10];
  const float* bsp = (const float*)d_in[11];
  const float* Wsq = (const float*)d_in[12];
  const float* bsq = (const float*)d_in[13];
  const float* Wsk = (const float*)d_in[14];
  const float* bsk = (const float*)d_in[15];
  const float* Wsv = (const float*)d_in[16];
  const float* bsv = (const float*)d_in[17];
  const float* Wso = (const float*)d_in[18];
  const float* bso = (const float*)d_in[19];
  const float* alpha = (const float*)d_in[20];
  float* out = (float*)d_out;

  char* ws = (char*)d_ws;
  u16* tokbf  = (u16*)ws;
  u16* qkv    = (u16*)(ws + 51380224);
  char* pp    = ws + 51380224 + 154140672;
  u16* WqkvT  = (u16*)pp; pp += 1572864;
  u16* WoT    = (u16*)pp; pp += 524288;
  u16* WsqkvT = (u16*)pp; pp += 1572864;
  u16* WsoT   = (u16*)pp; pp += 524288;
  u16* WspT   = (u16*)pp; pp += 196608;
  float* bqkv = (float*)pp; pp += 6144;
  float* bsqkv= (float*)pp; pp += 6144;
  u16* F2b    = (u16*)pp; pp += 1204224;
  u16* sd     = (u16*)pp; pp += 3211264;
  u16* qkvs   = (u16*)pp; pp += 9633792;
  u16* sopre  = (u16*)pp; pp += 3211264;
  float* sofin= (float*)pp; pp += 6422528;

  float* Sbuf = (float*)tokbf;
  u16* Pbuf   = (u16*)(ws + 9834496);
  u16* Vt     = (u16*)(ws + 9834496 + 5218304);

  // prep
  cvtbf<<<25088, 256, 0, stream>>>(tokens, tokbf);
  transT8<<<dim3(1024, 1, 8), 256, 0, stream>>>(
      Wq, Wk, Wv, Wo, Wsq, Wsk, Wsv, Wso,
      WqkvT, WqkvT + 262144, WqkvT + 524288, WoT,
      WsqkvT, WsqkvT + 262144, WsqkvT + 524288, WsoT);
  transT<<<384, 256, 0, stream>>>(Wsp, WspT, 192, 512);
  stack_bias<<<6, 256, 0, stream>>>(bq, bk, bv, bsq, bsk, bsv, bqkv, bsqkv);

  // spatial path
  gemm_bt512<<<dim3(12, 392), 512, 0, stream>>>(tokbf, 512, WqkvT, 512, bqkv, qkv, 1536, 50176, 1536, 512, 1);
  win_attn_mfma<<<4096, 256, 0, stream>>>(qkv, tokbf);
  gemm_bt<<<dim3(8, 392), 256, 0, stream>>>(tokbf, 512, 0, WoT, 512, 0, bo, qkv, 512, 0, 50176, 512, 512, 1);

  // spectral path
  dct_f2<<<3136, 192, 0, stream>>>(patches, F2b);
  gemm_bt<<<dim3(8, 25), 256, 0, stream>>>(F2b, 192, 0, WspT, 192, 0, bsp, sd, 512, 0, 3136, 512, 192, 1);
  gemm_bt<<<dim3(24, 25), 256, 0, stream>>>(sd, 512, 0, WsqkvT, 512, 0, bsqkv, qkvs, 1536, 0, 3136, 1536, 512, 1);
  gemm_bt<<<dim3(13, 7, 4), 256, 0, stream>>>(qkvs, 1536, (long)784 * 1536, qkvs + 512, 1536, (long)784 * 1536,
                                              nullptr, Sbuf, 784, (long)784 * 784, 784, 784, 512, 0);
  spec_softmax<<<3136, 256, 0, stream>>>(Sbuf, Pbuf);
  transV<<<6656, 256, 0, stream>>>(qkvs, Vt);
  gemm_bt<<<dim3(8, 7, 4), 256, 0, stream>>>(Pbuf, 832, (long)784 * 832, Vt, 832, (long)512 * 832,
                                             nullptr, sopre, 512, (long)784 * 512, 784, 512, 832, 1);
  gemm_bt<<<dim3(8, 25), 256, 0, stream>>>(sopre, 512, 0, WsoT, 512, 0, bso, sofin, 512, 0, 3136, 512, 512, 0);

  // combine + LN
  combine_ln<<<50176, 256, 0, stream>>>(tokens, qkv, sofin, alpha, out);
}